// Round 12
// baseline (948913.086 us; speedup 1.0000x reference)
//
#include <hip/hip_runtime.h>

typedef unsigned short ushort_t;
typedef __attribute__((ext_vector_type(4))) float f4;
typedef __attribute__((ext_vector_type(4))) int   i4;

__device__ __forceinline__ float b2f(ushort_t u){
  union { unsigned int i; float f; } v; v.i = ((unsigned int)u) << 16; return v.f;
}
__device__ __forceinline__ ushort_t f2b(float f){
  union { float f; unsigned int i; } v; v.f = f;
  unsigned int u = v.i;
  return (ushort_t)((u + 0x7fffu + ((u >> 16) & 1u)) >> 16);
}
__device__ __forceinline__ float sigm(float x){ return 1.f/(1.f + __expf(-x)); }

// ---------------- fp32 -> bf16 convert with optional col-slice and zero padding ----------------
__global__ void cvt_pad(const float* __restrict__ src, ushort_t* __restrict__ dst,
                        int Rsrc, int Csrc, int col0, int Ccopy, int Cdst, long total){
  long i = (long)blockIdx.x*256 + threadIdx.x;
  if (i >= total) return;
  int r = (int)(i / Cdst), c = (int)(i % Cdst);
  float v = 0.f;
  if (r < Rsrc && c < Ccopy) v = src[(long)r*Csrc + col0 + c];
  dst[i] = f2b(v);
}

// ---------------- decoder weight fold ----------------
__global__ void fold_w(const float* __restrict__ Wih, const float* __restrict__ Whh,
                       const float* __restrict__ ctxW, ushort_t* __restrict__ out, int poff){
  int p = blockIdx.x*256 + threadIdx.x;     // 0..1023
  int q = blockIdx.y;                       // 0..2047
  if (p >= 1024) return;
  float s = 0.f;
  #pragma unroll 8
  for (int e=0;e<64;e++) s += Wih[q*256 + 192 + e] * ctxW[e*1024 + p];
  if (p >= poff && p < poff + 512) s += Whh[q*512 + (p - poff)];
  out[(long)q*1024 + p] = f2b(s);
}

__global__ void fold_b(const float* __restrict__ b, const float* __restrict__ Wih,
                       const float* __restrict__ ctxb, float* __restrict__ out){
  int q = blockIdx.x*256 + threadIdx.x;
  if (q >= 2048) return;
  float s = b[q];
  #pragma unroll 8
  for (int e=0;e<64;e++) s += ctxb[e]*Wih[q*256 + 192 + e];
  out[q] = s;
}

// ---------------- z = mu + exp(0.5*lv)*noise ; reshape [K,S,N,E] -> [S*N, K*E] bf16 ----------------
__global__ void z_make(const float* __restrict__ mu, const float* __restrict__ lv,
                       const float* __restrict__ noise, ushort_t* __restrict__ zb){
  long i = (long)blockIdx.x*256 + threadIdx.x;
  if (i >= 3L*800*32*64) return;
  int e = (int)(i & 63); int n = (int)((i>>6) & 31);
  long r = i >> 11; int s = (int)(r % 800); int k = (int)(r / 800);
  float z = mu[i] + __expf(0.5f*lv[i]) * noise[i];
  zb[((long)(s*32 + n))*192 + k*64 + e] = f2b(z);
}

__global__ void dec_init(const float* __restrict__ h0, const float* __restrict__ c0,
                         ushort_t* __restrict__ prev, float* __restrict__ cDF, float* __restrict__ cDB){
  int i = blockIdx.x*256 + threadIdx.x;
  if (i < 32*1024) prev[i] = f2b(h0[i & 1023]);
  if (i < 32*512){ cDF[i] = c0[i & 511]; cDB[i] = c0[512 + (i & 511)]; }
}

__global__ void fill1(float* __restrict__ p, long n){
  long i = (long)blockIdx.x*256 + threadIdx.x;
  if (i < n) p[i] = 1.f;
}

// ---------------- bf16 MFMA GEMM: C[m][n] = sum_k A[m][k]*B[n][k] + bias[n] ----------------
#define GLD 40
__global__ __launch_bounds__(256) void gemm_bt(
    const ushort_t* __restrict__ A, int lda,
    const ushort_t* __restrict__ B, int ldb,
    const float* __restrict__ bias, int K, int Nreal, int mode, int ldc,
    float* __restrict__ outF, ushort_t* __restrict__ outB)
{
  __shared__ ushort_t Al[128*GLD];
  __shared__ ushort_t Bl[128*GLD];
  int tid = threadIdx.x;
  int m0 = blockIdx.y * 128;
  int n0 = blockIdx.x * 128;
  int l = tid & 63, w = tid >> 6;
  int wm = w & 1, wn = w >> 1;
  int srow = tid >> 2;
  int scg  = tid & 3;

  f4 acc[4][4];
  #pragma unroll
  for (int i=0;i<4;i++)
    #pragma unroll
    for (int j=0;j<4;j++) acc[i][j] = (f4){0.f,0.f,0.f,0.f};

  i4 pa0, pa1, pb0, pb1;
  {
    long ab = (long)(m0 + srow)*lda + scg*8;
    pa0 = *(const i4*)&A[ab];
    pa1 = *(const i4*)&A[ab + 64L*lda];
    long bb = (long)(n0 + srow)*ldb + scg*8;
    pb0 = *(const i4*)&B[bb];
    pb1 = *(const i4*)&B[bb + 64L*ldb];
  }
  for (int k0 = 0; k0 < K; k0 += 32){
    __syncthreads();
    *(i4*)&Al[srow*GLD + scg*8]      = pa0;
    *(i4*)&Al[(srow+64)*GLD + scg*8] = pa1;
    *(i4*)&Bl[srow*GLD + scg*8]      = pb0;
    *(i4*)&Bl[(srow+64)*GLD + scg*8] = pb1;
    __syncthreads();
    if (k0 + 32 < K){
      long ab = (long)(m0 + srow)*lda + k0 + 32 + scg*8;
      pa0 = *(const i4*)&A[ab];
      pa1 = *(const i4*)&A[ab + 64L*lda];
      long bb = (long)(n0 + srow)*ldb + k0 + 32 + scg*8;
      pb0 = *(const i4*)&B[bb];
      pb1 = *(const i4*)&B[bb + 64L*ldb];
    }
    int kg = (l>>4)*8;
    i4 av[4], bv[4];
    #pragma unroll
    for (int r=0;r<4;r++)
      av[r] = *(const i4*)&Al[(wm*64 + r*16 + (l&15))*GLD + kg];
    #pragma unroll
    for (int r=0;r<4;r++)
      bv[r] = *(const i4*)&Bl[(wn*64 + r*16 + (l&15))*GLD + kg];
    #pragma unroll
    for (int i=0;i<4;i++)
      #pragma unroll
      for (int j=0;j<4;j++)
        asm volatile("v_mfma_f32_16x16x32_bf16 %0, %1, %2, %0"
                     : "+v"(acc[i][j]) : "v"(av[i]), "v"(bv[j]));
  }
  asm volatile("s_nop 7\n\ts_nop 7\n\ts_nop 7");
  int row_l = (l>>4)*4, col_l = l&15;
  #pragma unroll
  for (int i=0;i<4;i++){
    #pragma unroll
    for (int j=0;j<4;j++){
      int n = n0 + wn*64 + j*16 + col_l;
      if (n >= Nreal) continue;
      float bb = bias[n];
      #pragma unroll
      for (int r=0;r<4;r++){
        int m = m0 + wm*64 + i*16 + row_l + r;
        float v = acc[i][j][r] + bb;
        if (mode == 0){
          outF[(long)m*ldc + n] = v;
        } else if (mode == 1){
          outB[(long)m*ldc + n] = f2b(v);
        } else if (mode == 2){
          outB[(long)m*ldc + n] = f2b(tanhf(v));
        } else {
          outF[(long)(n>>6)*1638400 + (long)m*64 + (n&63)] = v;
        }
      }
    }
  }
}

// ---------------- XCD-pinned persistent LSTM chunk ----------------
// 1024 blocks launched; blocks on XCD0 claim fwd slots, XCD1 claim bwd slots (32 each);
// all others exit. Worker slot u owns 16 units (64 gate rows: wave = gate, full K).
// REMOTE=0 (enc): h exchange via local XCD L2 (plain stores, sc0 loads, plain flags).
// REMOTE=1 (dec): cross-dir exchange via L3 (sc0 sc1 stores/loads/flags).
// Flags monotonic per call: flag[slot] = fbase+js+1 after step js.
template<int KA, int REMOTE>
__global__ __launch_bounds__(256) void lstm_xcd(
    int nsteps, unsigned fbase,
    const ushort_t* __restrict__ initAf, const ushort_t* __restrict__ initAb,
    ushort_t* __restrict__ outF, ushort_t* __restrict__ outB,
    long oStrF, long oStrB, long aOffF, long aOffB,
    const ushort_t* __restrict__ preFb, const ushort_t* __restrict__ preBb,
    long pStrF, long pStrB,
    const ushort_t* __restrict__ Wf, const ushort_t* __restrict__ Wb,
    float* __restrict__ cF, float* __restrict__ cB,
    unsigned* claims, unsigned* flags)
{
  constexpr int H = KA/512;
  __shared__ ushort_t Als[32*520];      // A half-tile, +8 pad
  __shared__ float gl[4][32][17];       // per-gate results
  __shared__ int slotS;
  int tid = threadIdx.x;
  if (tid == 0){
    unsigned xcd = 0xffu;
    asm volatile("s_getreg_b32 %0, hwreg(HW_REG_XCC_ID)" : "=s"(xcd));
    int d = (xcd == 0u) ? 0 : ((xcd == 1u) ? 1 : -1);
    int s = -1;
    if (d >= 0){
      unsigned v = __hip_atomic_fetch_add(&claims[d*16], 1u, __ATOMIC_RELAXED, __HIP_MEMORY_SCOPE_WORKGROUP);
      if (v < 32u) s = (int)v;
    }
    slotS = (s < 0) ? -1 : (d*32 + s);
  }
  __syncthreads();
  int slot = slotS;
  if (slot < 0) return;
  int dir = slot >> 5, u = slot & 31, U0 = u*16;

  const ushort_t* W     = dir ? Wb : Wf;
  float*          c     = dir ? cB : cF;
  const ushort_t* preB0 = dir ? preBb : preFb;
  long pStr             = dir ? pStrB : pStrF;
  long oStr             = dir ? oStrB : oStrF;
  ushort_t* outBase     = dir ? outB : outF;
  long aOff             = dir ? aOffB : aOffF;
  const ushort_t* initA = dir ? initAb : initAf;
  unsigned* myflag      = flags + slot*16;

  int l = tid & 63, w = tid >> 6;       // wave = gate
  int col = l & 15, kq = l >> 4;
  const ushort_t* Wr = &W[(long)(w*512 + U0 + col)*KA + kq*8];

  int on = tid >> 3, ou = (tid & 7)*2;  // output ownership: (n, unit-pair)
  float c0 = c[on*512 + U0 + ou];
  float c1 = c[on*512 + U0 + ou + 1];

  for (int js = 0; js < nsteps; ++js){
    // pre prefetch (flag-independent)
    const ushort_t* prow = preB0 + js*pStr + on*2048 + U0 + ou;
    unsigned pr0 = *(const unsigned*)&prow[0];
    unsigned pr1 = *(const unsigned*)&prow[512];
    unsigned pr2 = *(const unsigned*)&prow[1024];
    unsigned pr3 = *(const unsigned*)&prow[1536];

    if (js > 0){
      if (tid < 64){
        int nf = REMOTE ? 64 : 32;
        unsigned tgt = fbase + (unsigned)js;
        const unsigned* fp = flags + (REMOTE ? tid : (dir*32 + (tid & 31)))*16;
        bool ok = tid >= nf;
        int spins = 0;
        while (!ok){
          unsigned v;
          if (REMOTE) asm volatile("global_load_dword %0, %1, off sc0 sc1\n\ts_waitcnt vmcnt(0)" : "=v"(v) : "v"(fp));
          else        asm volatile("global_load_dword %0, %1, off sc0\n\ts_waitcnt vmcnt(0)" : "=v"(v) : "v"(fp));
          ok = (v >= tgt);
          if (++spins > 8000) break;   // bounded: no harness hang on pathology
        }
      }
      __syncthreads();
      __builtin_amdgcn_sched_barrier(0);
    }

    const ushort_t* A = (js == 0) ? initA
        : (const ushort_t*)(outBase + (js-1)*oStr + aOff);

    f4 acc0 = (f4){0.f,0.f,0.f,0.f}, acc1 = (f4){0.f,0.f,0.f,0.f};
    #pragma unroll
    for (int half = 0; half < H; ++half){
      i4 st[8];
      #pragma unroll
      for (int i = 0; i < 8; ++i){
        int ci = tid + i*256;
        int r = ci >> 6, ch = ci & 63;
        const ushort_t* src = A + r*1024 + half*512 + ch*8;
        if (REMOTE) asm volatile("global_load_dwordx4 %0, %1, off sc0 sc1" : "=v"(st[i]) : "v"(src));
        else        asm volatile("global_load_dwordx4 %0, %1, off sc0"     : "=v"(st[i]) : "v"(src));
      }
      asm volatile("s_waitcnt vmcnt(0)" ::: "memory");
      __syncthreads();                  // prior Als readers done
      #pragma unroll
      for (int i = 0; i < 8; ++i){
        int ci = tid + i*256;
        int r = ci >> 6, ch = ci & 63;
        *(i4*)&Als[r*520 + ch*8] = st[i];
      }
      __syncthreads();                  // staged
      #pragma unroll
      for (int kk = 0; kk < 16; ++kk){
        i4 a0v = *(const i4*)&Als[col*520 + kk*32 + kq*8];
        i4 a1v = *(const i4*)&Als[(col+16)*520 + kk*32 + kq*8];
        i4 bv  = *(const i4*)&Wr[half*512 + kk*32];
        asm volatile("v_mfma_f32_16x16x32_bf16 %0, %1, %2, %0" : "+v"(acc0) : "v"(a0v), "v"(bv));
        asm volatile("v_mfma_f32_16x16x32_bf16 %0, %1, %2, %0" : "+v"(acc1) : "v"(a1v), "v"(bv));
      }
    }
    asm volatile("s_nop 7\n\ts_nop 7\n\ts_nop 7");
    #pragma unroll
    for (int r = 0; r < 4; ++r){
      gl[w][kq*4 + r][col]      = acc0[r];
      gl[w][kq*4 + r + 16][col] = acc1[r];
    }
    __syncthreads();
    {
      float gi = gl[0][on][ou] + b2f((ushort_t)(pr0 & 0xffff));
      float gI = gl[0][on][ou+1] + b2f((ushort_t)(pr0 >> 16));
      float gf = gl[1][on][ou] + b2f((ushort_t)(pr1 & 0xffff));
      float gF = gl[1][on][ou+1] + b2f((ushort_t)(pr1 >> 16));
      float gg = gl[2][on][ou] + b2f((ushort_t)(pr2 & 0xffff));
      float gG = gl[2][on][ou+1] + b2f((ushort_t)(pr2 >> 16));
      float go = gl[3][on][ou] + b2f((ushort_t)(pr3 & 0xffff));
      float gO = gl[3][on][ou+1] + b2f((ushort_t)(pr3 >> 16));
      float i0 = sigm(gi), i1 = sigm(gI);
      float f0_ = sigm(gf), f1_ = sigm(gF);
      float g0_ = tanhf(gg), g1_ = tanhf(gG);
      float o0 = sigm(go), o1 = sigm(gO);
      c0 = f0_*c0 + i0*g0_;
      c1 = f1_*c1 + i1*g1_;
      float h0 = o0*tanhf(c0), h1 = o1*tanhf(c1);
      unsigned pk = (unsigned)f2b(h0) | ((unsigned)f2b(h1) << 16);
      ushort_t* outp = outBase + js*oStr;
      unsigned* oaddr = (unsigned*)&outp[on*1024 + U0 + ou];
      if (REMOTE) asm volatile("global_store_dword %0, %1, off sc0 sc1" :: "v"(oaddr), "v"(pk) : "memory");
      else *oaddr = pk;
    }
    asm volatile("s_waitcnt vmcnt(0)" ::: "memory");   // h at coherence point
    __syncthreads();
    if (tid == 0){
      unsigned fv = fbase + (unsigned)js + 1u;
      if (REMOTE) asm volatile("global_store_dword %0, %1, off sc0 sc1" :: "v"(myflag), "v"(fv) : "memory");
      else *myflag = fv;
    }
  }
  c[on*512 + U0 + ou]     = c0;
  c[on*512 + U0 + ou + 1] = c1;
}

extern "C" void kernel_launch(void* const* d_in, const int* in_sizes, int n_in,
                              void* d_out, int out_size, void* d_ws, size_t ws_size,
                              hipStream_t stream)
{
  const float* inp    = (const float*)d_in[0];
  const float* noise  = (const float*)d_in[1];
  const float* e0f_Wih=(const float*)d_in[2];
  const float* e0f_Whh=(const float*)d_in[3];
  const float* e0f_b  =(const float*)d_in[4];
  const float* e0b_Wih=(const float*)d_in[5];
  const float* e0b_Whh=(const float*)d_in[6];
  const float* e0b_b  =(const float*)d_in[7];
  const float* e1f_Wih=(const float*)d_in[8];
  const float* e1f_Whh=(const float*)d_in[9];
  const float* e1f_b  =(const float*)d_in[10];
  const float* e1b_Wih=(const float*)d_in[11];
  const float* e1b_Whh=(const float*)d_in[12];
  const float* e1b_b  =(const float*)d_in[13];
  const float* df_Wih =(const float*)d_in[14];
  const float* df_Whh =(const float*)d_in[15];
  const float* df_b   =(const float*)d_in[16];
  const float* db_Wih =(const float*)d_in[17];
  const float* db_Whh =(const float*)d_in[18];
  const float* db_b   =(const float*)d_in[19];
  const float* mu_W   =(const float*)d_in[20];
  const float* mu_b   =(const float*)d_in[21];
  const float* sig_W  =(const float*)d_in[22];
  const float* sig_b  =(const float*)d_in[23];
  const float* h0     =(const float*)d_in[24];
  const float* c0     =(const float*)d_in[25];
  const float* ctx_W  =(const float*)d_in[26];
  const float* ctx_b  =(const float*)d_in[27];
  const float* feat_W =(const float*)d_in[28];
  const float* feat_b =(const float*)d_in[29];
  const float* score_W=(const float*)d_in[30];
  const float* score_b=(const float*)d_in[31];

  float* dout = (float*)d_out;
  const long Y_OFF  = 0;
  const long MU_OFF = 8217600;
  const long LV_OFF = 13132800;
  const long MK_OFF = 18048000;

  // ---------------- workspace layout (~178 MB with aliasing) ----------------
  char* ws = (char*)d_ws;
  size_t off = 0;
  auto alloc = [&](size_t bytes)->char*{
    char* p = ws + off; off += (bytes + 255) & ~(size_t)255; return p;
  };
  char* regionA = alloc(25600L*1024*2);   // x1 (enc) -> dec (decoder/head)
  char* regionB = alloc(25600L*1024*2);   // inpb -> x2 -> feat chunks
  ushort_t* preFc = (ushort_t*)alloc(3200L*2048*2);
  ushort_t* preBc = (ushort_t*)alloc(3200L*2048*2);
  ushort_t* zb    = (ushort_t*)alloc(25600L*192*2);
  ushort_t* w_e0f = (ushort_t*)alloc(2048L*352*2);
  ushort_t* w_e0b = (ushort_t*)alloc(2048L*352*2);
  ushort_t* w_e1f = (ushort_t*)alloc(2048L*1024*2);
  ushort_t* w_e1b = (ushort_t*)alloc(2048L*1024*2);
  ushort_t* w_h0f = (ushort_t*)alloc(2048L*512*2);
  ushort_t* w_h0b = (ushort_t*)alloc(2048L*512*2);
  ushort_t* w_h1f = (ushort_t*)alloc(2048L*512*2);
  ushort_t* w_h1b = (ushort_t*)alloc(2048L*512*2);
  ushort_t* w_mu  = (ushort_t*)alloc(256L*1024*2);
  ushort_t* w_sig = (ushort_t*)alloc(256L*1024*2);
  ushort_t* w_dzf = (ushort_t*)alloc(2048L*192*2);
  ushort_t* w_dzb = (ushort_t*)alloc(2048L*192*2);
  ushort_t* BfT   = (ushort_t*)alloc(2048L*1024*2);
  ushort_t* BbT   = (ushort_t*)alloc(2048L*1024*2);
  ushort_t* w_feat= (ushort_t*)alloc(2048L*1024*2);
  ushort_t* w_scr = (ushort_t*)alloc(384L*2048*2);
  float* bdF  = (float*)alloc(2048*4);
  float* bdB  = (float*)alloc(2048*4);
  float* cEF  = (float*)alloc(32L*512*4);
  float* cEB  = (float*)alloc(32L*512*4);
  float* cDF  = (float*)alloc(32L*512*4);
  float* cDB  = (float*)alloc(32L*512*4);
  ushort_t* zerob = (ushort_t*)alloc(32L*1024*2);
  ushort_t* pinit = (ushort_t*)alloc(32L*1024*2);
  unsigned* flags  = (unsigned*)alloc(4096);   // 64 flags x 64B lines
  unsigned* claims = (unsigned*)alloc(128);    // 2 counters x 64B lines

  ushort_t* x1    = (ushort_t*)regionA;
  ushort_t* dec   = (ushort_t*)regionA;
  ushort_t* inpb  = (ushort_t*)regionB;
  ushort_t* x2    = (ushort_t*)regionB;
  ushort_t* featc = (ushort_t*)regionB;

  if (ws_size < off){
    hipMemsetAsync(d_out, 0, (size_t)out_size*4, stream);
    return;
  }

  auto CVT=[&](const float* s, ushort_t* d, int Rs, int Cs, int c0_, int Cc, int Cd, int Rd){
    long tot = (long)Rd*Cd;
    int blocks = (int)((tot + 255)/256);
    cvt_pad<<<blocks, 256, 0, stream>>>(s, d, Rs, Cs, c0_, Cc, Cd, tot);
  };
  auto GEMM=[&](const ushort_t* A, int lda, const ushort_t* B, int ldb, const float* bias,
                int K, int Nreal, int mode, int ldc, float* oF, ushort_t* oB, int nt, int mt){
    gemm_bt<<<dim3(nt,mt), 256, 0, stream>>>(A, lda, B, ldb, bias, K, Nreal, mode, ldc, oF, oB);
  };

  // ---------------- weight/input conversions ----------------
  CVT(inp,     inpb,  25600, 321, 0, 321, 352, 25600);
  CVT(e0f_Wih, w_e0f, 2048, 321, 0, 321, 352, 2048);
  CVT(e0b_Wih, w_e0b, 2048, 321, 0, 321, 352, 2048);
  CVT(e1f_Wih, w_e1f, 2048, 1024, 0, 1024, 1024, 2048);
  CVT(e1b_Wih, w_e1b, 2048, 1024, 0, 1024, 1024, 2048);
  CVT(e0f_Whh, w_h0f, 2048, 512, 0, 512, 512, 2048);
  CVT(e0b_Whh, w_h0b, 2048, 512, 0, 512, 512, 2048);
  CVT(e1f_Whh, w_h1f, 2048, 512, 0, 512, 512, 2048);
  CVT(e1b_Whh, w_h1b, 2048, 512, 0, 512, 512, 2048);
  CVT(mu_W,    w_mu,  192, 1024, 0, 1024, 1024, 256);
  CVT(sig_W,   w_sig, 192, 1024, 0, 1024, 1024, 256);
  CVT(df_Wih,  w_dzf, 2048, 256, 0, 192, 192, 2048);
  CVT(db_Wih,  w_dzb, 2048, 256, 0, 192, 192, 2048);
  CVT(feat_W,  w_feat,2048, 1024, 0, 1024, 1024, 2048);
  CVT(score_W, w_scr, 321, 2048, 0, 2048, 2048, 384);
  fold_w<<<dim3(4,2048), 256, 0, stream>>>(df_Wih, df_Whh, ctx_W, BfT, 0);
  fold_w<<<dim3(4,2048), 256, 0, stream>>>(db_Wih, db_Whh, ctx_W, BbT, 512);
  fold_b<<<8, 256, 0, stream>>>(df_b, df_Wih, ctx_b, bdF);
  fold_b<<<8, 256, 0, stream>>>(db_b, db_Wih, ctx_b, bdB);
  hipMemsetAsync(zerob, 0, 32L*1024*2, stream);
  hipMemsetAsync(cEF, 0, 32L*512*4, stream);
  hipMemsetAsync(cEB, 0, 32L*512*4, stream);
  hipMemsetAsync(flags, 0, 4096, stream);
  dec_init<<<128, 256, 0, stream>>>(h0, c0, pinit, cDF, cDB);

  const int C = 100;
  const int RPC = C*32;
  unsigned fbase = 0;

  // ---------------- encoder layer 0 ----------------
  for (int c = 0; c < 8; c++){
    int f0 = c*C;
    int b0 = 800 - (c+1)*C;
    GEMM(inpb + (long)f0*32*352, 352, w_e0f, 352, e0f_b, 352, 2048, 1, 2048, nullptr, preFc, 16, 25);
    GEMM(inpb + (long)b0*32*352, 352, w_e0b, 352, e0b_b, 352, 2048, 1, 2048, nullptr, preBc, 16, 25);
    hipMemsetAsync(claims, 0, 128, stream);
    lstm_xcd<512,0><<<1024, 256, 0, stream>>>(C, fbase,
      f0 ? x1 + (long)(f0-1)*32768 : zerob,
      f0 ? x1 + (long)(800-f0)*32768 + 512 : zerob,
      x1 + (long)f0*32768, x1 + (long)(799-f0)*32768 + 512,
      32768L, -32768L, 0L, 0L,
      preFc, preBc + (long)(C-1)*65536, 65536L, -65536L,
      w_h0f, w_h0b, cEF, cEB, claims, flags);
    fbase += (unsigned)C;
  }

  // ---------------- encoder layer 1 ----------------
  hipMemsetAsync(cEF, 0, 32L*512*4, stream);
  hipMemsetAsync(cEB, 0, 32L*512*4, stream);
  for (int c = 0; c < 8; c++){
    int f0 = c*C;
    int b0 = 800 - (c+1)*C;
    GEMM(x1 + (long)f0*32768, 1024, w_e1f, 1024, e1f_b, 1024, 2048, 1, 2048, nullptr, preFc, 16, 25);
    GEMM(x1 + (long)b0*32768, 1024, w_e1b, 1024, e1b_b, 1024, 2048, 1, 2048, nullptr, preBc, 16, 25);
    hipMemsetAsync(claims, 0, 128, stream);
    lstm_xcd<512,0><<<1024, 256, 0, stream>>>(C, fbase,
      f0 ? x2 + (long)(f0-1)*32768 : zerob,
      f0 ? x2 + (long)(800-f0)*32768 + 512 : zerob,
      x2 + (long)f0*32768, x2 + (long)(799-f0)*32768 + 512,
      32768L, -32768L, 0L, 0L,
      preFc, preBc + (long)(C-1)*65536, 65536L, -65536L,
      w_h1f, w_h1b, cEF, cEB, claims, flags);
    fbase += (unsigned)C;
  }

  // ---------------- latent heads + z ----------------
  GEMM(x2, 1024, w_mu,  1024, mu_b,  1024, 192, 3, 0, dout + MU_OFF, nullptr, 2, 200);
  GEMM(x2, 1024, w_sig, 1024, sig_b, 1024, 192, 3, 0, dout + LV_OFF, nullptr, 2, 200);
  z_make<<<(int)((4915200 + 255)/256), 256, 0, stream>>>(dout + MU_OFF, dout + LV_OFF, noise, zb);

  // ---------------- decoder ----------------
  for (int c = 0; c < 8; c++){
    int f0 = c*C;
    GEMM(zb + (long)f0*32*192, 192, w_dzf, 192, bdF, 192, 2048, 1, 2048, nullptr, preFc, 16, 25);
    GEMM(zb + (long)f0*32*192, 192, w_dzb, 192, bdB, 192, 2048, 1, 2048, nullptr, preBc, 16, 25);
    hipMemsetAsync(claims, 0, 128, stream);
    lstm_xcd<1024,1><<<1024, 256, 0, stream>>>(C, fbase,
      f0 ? dec + (long)(f0-1)*32768 : pinit,
      f0 ? dec + (long)(f0-1)*32768 : pinit,
      dec + (long)f0*32768, dec + (long)f0*32768 + 512,
      32768L, 32768L, 0L, -512L,
      preFc, preBc, 65536L, 65536L,
      BfT, BbT, cDF, cDB, claims, flags);
    fbase += (unsigned)C;
  }

  // ---------------- output head ----------------
  for (int c = 0; c < 8; c++){
    long r0 = (long)c*RPC;
    GEMM(dec + r0*1024, 1024, w_feat, 1024, feat_b, 1024, 2048, 2, 2048, nullptr, featc, 16, 25);
    GEMM(featc, 2048, w_scr, 2048, score_b, 2048, 321, 0, 321, dout + Y_OFF + r0*321, nullptr, 3, 25);
  }
  fill1<<<100, 256, 0, stream>>>(dout + MK_OFF, 25600);
}

// Round 14
// 14472.902 us; speedup vs baseline: 65.5648x; 65.5648x over previous
//
#include <hip/hip_runtime.h>

typedef unsigned short ushort_t;
typedef __attribute__((ext_vector_type(4))) float f4;
typedef __attribute__((ext_vector_type(4))) int   i4;

__device__ __forceinline__ float b2f(ushort_t u){
  union { unsigned int i; float f; } v; v.i = ((unsigned int)u) << 16; return v.f;
}
__device__ __forceinline__ ushort_t f2b(float f){
  union { float f; unsigned int i; } v; v.f = f;
  unsigned int u = v.i;
  return (ushort_t)((u + 0x7fffu + ((u >> 16) & 1u)) >> 16);
}
__device__ __forceinline__ float sigm(float x){ return 1.f/(1.f + __expf(-x)); }

// ---------------- fp32 -> bf16 convert with optional col-slice and zero padding ----------------
__global__ void cvt_pad(const float* __restrict__ src, ushort_t* __restrict__ dst,
                        int Rsrc, int Csrc, int col0, int Ccopy, int Cdst, long total){
  long i = (long)blockIdx.x*256 + threadIdx.x;
  if (i >= total) return;
  int r = (int)(i / Cdst), c = (int)(i % Cdst);
  float v = 0.f;
  if (r < Rsrc && c < Ccopy) v = src[(long)r*Csrc + col0 + c];
  dst[i] = f2b(v);
}

// ---------------- decoder weight fold ----------------
__global__ void fold_w(const float* __restrict__ Wih, const float* __restrict__ Whh,
                       const float* __restrict__ ctxW, ushort_t* __restrict__ out, int poff){
  int p = blockIdx.x*256 + threadIdx.x;     // 0..1023
  int q = blockIdx.y;                       // 0..2047
  if (p >= 1024) return;
  float s = 0.f;
  #pragma unroll 8
  for (int e=0;e<64;e++) s += Wih[q*256 + 192 + e] * ctxW[e*1024 + p];
  if (p >= poff && p < poff + 512) s += Whh[q*512 + (p - poff)];
  out[(long)q*1024 + p] = f2b(s);
}

__global__ void fold_b(const float* __restrict__ b, const float* __restrict__ Wih,
                       const float* __restrict__ ctxb, float* __restrict__ out){
  int q = blockIdx.x*256 + threadIdx.x;
  if (q >= 2048) return;
  float s = b[q];
  #pragma unroll 8
  for (int e=0;e<64;e++) s += ctxb[e]*Wih[q*256 + 192 + e];
  out[q] = s;
}

// ---------------- z = mu + exp(0.5*lv)*noise ; reshape [K,S,N,E] -> [S*N, K*E] bf16 ----------------
__global__ void z_make(const float* __restrict__ mu, const float* __restrict__ lv,
                       const float* __restrict__ noise, ushort_t* __restrict__ zb){
  long i = (long)blockIdx.x*256 + threadIdx.x;
  if (i >= 3L*800*32*64) return;
  int e = (int)(i & 63); int n = (int)((i>>6) & 31);
  long r = i >> 11; int s = (int)(r % 800); int k = (int)(r / 800);
  float z = mu[i] + __expf(0.5f*lv[i]) * noise[i];
  zb[((long)(s*32 + n))*192 + k*64 + e] = f2b(z);
}

__global__ void dec_init(const float* __restrict__ h0, const float* __restrict__ c0,
                         ushort_t* __restrict__ prev, float* __restrict__ cDF, float* __restrict__ cDB){
  int i = blockIdx.x*256 + threadIdx.x;
  if (i < 32*1024) prev[i] = f2b(h0[i & 1023]);
  if (i < 32*512){ cDF[i] = c0[i & 511]; cDB[i] = c0[512 + (i & 511)]; }
}

__global__ void fill1(float* __restrict__ p, long n){
  long i = (long)blockIdx.x*256 + threadIdx.x;
  if (i < n) p[i] = 1.f;
}

// ---------------- bf16 MFMA GEMM: C[m][n] = sum_k A[m][k]*B[n][k] + bias[n] ----------------
// A: [M][lda] bf16 (M = gridDim.y*128), B: [Ntiles*128][ldb] bf16 (rows zero-padded), K mult of 32.
// mode 0: fp32 C[m*ldc+n]; 1: bf16; 2: tanh->bf16; 3: fp32 mu-scatter (k=n>>6,e=n&63; out[k*1638400+m*64+e])
#define GLD 40
__global__ __launch_bounds__(256) void gemm_bt(
    const ushort_t* __restrict__ A, int lda,
    const ushort_t* __restrict__ B, int ldb,
    const float* __restrict__ bias, int K, int Nreal, int mode, int ldc,
    float* __restrict__ outF, ushort_t* __restrict__ outB)
{
  __shared__ ushort_t Al[128*GLD];
  __shared__ ushort_t Bl[128*GLD];
  int tid = threadIdx.x;
  int m0 = blockIdx.y * 128;
  int n0 = blockIdx.x * 128;
  int l = tid & 63, w = tid >> 6;
  int wm = w & 1, wn = w >> 1;
  int srow = tid >> 2;       // 0..63
  int scg  = tid & 3;        // 0..3 (16B chunks of the 64B-wide K-tile rows)

  f4 acc[4][4];
  #pragma unroll
  for (int i=0;i<4;i++)
    #pragma unroll
    for (int j=0;j<4;j++) acc[i][j] = (f4){0.f,0.f,0.f,0.f};

  i4 pa0, pa1, pb0, pb1;
  {
    long ab = (long)(m0 + srow)*lda + scg*8;
    pa0 = *(const i4*)&A[ab];
    pa1 = *(const i4*)&A[ab + 64L*lda];
    long bb = (long)(n0 + srow)*ldb + scg*8;
    pb0 = *(const i4*)&B[bb];
    pb1 = *(const i4*)&B[bb + 64L*ldb];
  }
  for (int k0 = 0; k0 < K; k0 += 32){
    __syncthreads();
    *(i4*)&Al[srow*GLD + scg*8]      = pa0;
    *(i4*)&Al[(srow+64)*GLD + scg*8] = pa1;
    *(i4*)&Bl[srow*GLD + scg*8]      = pb0;
    *(i4*)&Bl[(srow+64)*GLD + scg*8] = pb1;
    __syncthreads();
    if (k0 + 32 < K){
      long ab = (long)(m0 + srow)*lda + k0 + 32 + scg*8;
      pa0 = *(const i4*)&A[ab];
      pa1 = *(const i4*)&A[ab + 64L*lda];
      long bb = (long)(n0 + srow)*ldb + k0 + 32 + scg*8;
      pb0 = *(const i4*)&B[bb];
      pb1 = *(const i4*)&B[bb + 64L*ldb];
    }
    int kg = (l>>4)*8;
    i4 av[4], bv[4];
    #pragma unroll
    for (int r=0;r<4;r++)
      av[r] = *(const i4*)&Al[(wm*64 + r*16 + (l&15))*GLD + kg];
    #pragma unroll
    for (int r=0;r<4;r++)
      bv[r] = *(const i4*)&Bl[(wn*64 + r*16 + (l&15))*GLD + kg];
    #pragma unroll
    for (int i=0;i<4;i++)
      #pragma unroll
      for (int j=0;j<4;j++)
        asm volatile("v_mfma_f32_16x16x32_bf16 %0, %1, %2, %0"
                     : "+v"(acc[i][j]) : "v"(av[i]), "v"(bv[j]));
  }
  asm volatile("s_nop 7\n\ts_nop 7\n\ts_nop 7");
  int row_l = (l>>4)*4, col_l = l&15;
  #pragma unroll
  for (int i=0;i<4;i++){
    #pragma unroll
    for (int j=0;j<4;j++){
      int n = n0 + wn*64 + j*16 + col_l;
      if (n >= Nreal) continue;
      float bb = bias[n];
      #pragma unroll
      for (int r=0;r<4;r++){
        int m = m0 + wm*64 + i*16 + row_l + r;
        float v = acc[i][j][r] + bb;
        if (mode == 0){
          outF[(long)m*ldc + n] = v;
        } else if (mode == 1){
          outB[(long)m*ldc + n] = f2b(v);
        } else if (mode == 2){
          outB[(long)m*ldc + n] = f2b(tanhf(v));
        } else {
          outF[(long)(n>>6)*1638400 + (long)m*64 + (n&63)] = v;
        }
      }
    }
  }
}

// ---------------- fused LSTM step, all-CU version ----------------
// 256 blocks: dir = bx>>7, 4 hidden units u0 = (bx&127)*4 (all 4 gates).
// Waves split K into 4 slices; partial C[32x16] summed via LDS.
// gates[n][g*512+j] = pre[n][g*512+j] + sum_k A[n][k]*W[g*512+j][k] ; then cell update.
template<int KA>
__global__ __launch_bounds__(256) void lstm_step(
    const ushort_t* __restrict__ Af, const ushort_t* __restrict__ Ab,  // prev h, row stride 1024
    const ushort_t* __restrict__ preF, const ushort_t* __restrict__ preB, // [32][2048] chunk rows
    const ushort_t* __restrict__ Wf, const ushort_t* __restrict__ Wb,  // [2048][KA], row = g*512+j
    float* __restrict__ cF, float* __restrict__ cB,                    // [32][512]
    ushort_t* __restrict__ outF, ushort_t* __restrict__ outB)          // row stride 1024
{
  __shared__ float gl[4][32][17];
  int tid = threadIdx.x;
  int dir = blockIdx.x >> 7;
  int u0  = (blockIdx.x & 127) << 2;   // 4 hidden units
  const ushort_t* A   = dir ? Ab   : Af;
  const ushort_t* pre = dir ? preB : preF;
  const ushort_t* W   = dir ? Wb   : Wf;
  float* c            = dir ? cB   : cF;
  ushort_t* out       = dir ? outB : outF;

  int l = tid & 63, w = tid >> 6;
  int col = l & 15;                    // out col: gate g = col>>2, unit u0+(col&3)
  constexpr int KW = KA/4;             // per-wave K slice
  int kgw = w*KW + (l>>4)*8;
  int wrow = (col>>2)*512 + u0 + (col&3);
  const ushort_t* Wr  = &W[(long)wrow*KA + kgw];
  const ushort_t* Ar0 = &A[col*1024 + kgw];
  const ushort_t* Ar1 = &A[(col+16)*1024 + kgw];
  f4 acc0 = (f4){0.f,0.f,0.f,0.f}, acc1 = (f4){0.f,0.f,0.f,0.f};
  #pragma unroll
  for (int k0=0;k0<KW;k0+=32){
    i4 b  = *(const i4*)&Wr[k0];
    i4 a0 = *(const i4*)&Ar0[k0];
    i4 a1 = *(const i4*)&Ar1[k0];
    asm volatile("v_mfma_f32_16x16x32_bf16 %0, %1, %2, %0" : "+v"(acc0) : "v"(a0), "v"(b));
    asm volatile("v_mfma_f32_16x16x32_bf16 %0, %1, %2, %0" : "+v"(acc1) : "v"(a1), "v"(b));
  }
  asm volatile("s_nop 7\n\ts_nop 7\n\ts_nop 7");
  int rl = (l>>4)*4;
  #pragma unroll
  for (int r=0;r<4;r++){
    gl[w][rl + r][col]      = acc0[r];
    gl[w][rl + r + 16][col] = acc1[r];
  }
  __syncthreads();
  if (tid < 128){
    int n = tid >> 2, ju = tid & 3;
    int j = u0 + ju;
    float gs[4];
    #pragma unroll
    for (int g=0; g<4; g++){
      int cc = g*4 + ju;
      gs[g] = gl[0][n][cc] + gl[1][n][cc] + gl[2][n][cc] + gl[3][n][cc];
    }
    float gi = gs[0] + b2f(pre[n*2048 + j]);
    float gf = gs[1] + b2f(pre[n*2048 + 512 + j]);
    float gg = gs[2] + b2f(pre[n*2048 + 1024 + j]);
    float go = gs[3] + b2f(pre[n*2048 + 1536 + j]);
    float ii = sigm(gi), ff = sigm(gf), g2 = tanhf(gg), oo = sigm(go);
    float cn = ff*c[n*512 + j] + ii*g2;
    c[n*512 + j] = cn;
    out[n*1024 + j] = f2b(oo*tanhf(cn));
  }
}

extern "C" void kernel_launch(void* const* d_in, const int* in_sizes, int n_in,
                              void* d_out, int out_size, void* d_ws, size_t ws_size,
                              hipStream_t stream)
{
  const float* inp    = (const float*)d_in[0];
  const float* noise  = (const float*)d_in[1];
  const float* e0f_Wih=(const float*)d_in[2];
  const float* e0f_Whh=(const float*)d_in[3];
  const float* e0f_b  =(const float*)d_in[4];
  const float* e0b_Wih=(const float*)d_in[5];
  const float* e0b_Whh=(const float*)d_in[6];
  const float* e0b_b  =(const float*)d_in[7];
  const float* e1f_Wih=(const float*)d_in[8];
  const float* e1f_Whh=(const float*)d_in[9];
  const float* e1f_b  =(const float*)d_in[10];
  const float* e1b_Wih=(const float*)d_in[11];
  const float* e1b_Whh=(const float*)d_in[12];
  const float* e1b_b  =(const float*)d_in[13];
  const float* df_Wih =(const float*)d_in[14];
  const float* df_Whh =(const float*)d_in[15];
  const float* df_b   =(const float*)d_in[16];
  const float* db_Wih =(const float*)d_in[17];
  const float* db_Whh =(const float*)d_in[18];
  const float* db_b   =(const float*)d_in[19];
  const float* mu_W   =(const float*)d_in[20];
  const float* mu_b   =(const float*)d_in[21];
  const float* sig_W  =(const float*)d_in[22];
  const float* sig_b  =(const float*)d_in[23];
  const float* h0     =(const float*)d_in[24];
  const float* c0     =(const float*)d_in[25];
  const float* ctx_W  =(const float*)d_in[26];
  const float* ctx_b  =(const float*)d_in[27];
  const float* feat_W =(const float*)d_in[28];
  const float* feat_b =(const float*)d_in[29];
  const float* score_W=(const float*)d_in[30];
  const float* score_b=(const float*)d_in[31];

  float* dout = (float*)d_out;
  const long Y_OFF  = 0;
  const long MU_OFF = 8217600;
  const long LV_OFF = 13132800;
  const long MK_OFF = 18048000;

  // ---------------- workspace layout (~178 MB with aliasing) ----------------
  char* ws = (char*)d_ws;
  size_t off = 0;
  auto alloc = [&](size_t bytes)->char*{
    char* p = ws + off; off += (bytes + 255) & ~(size_t)255; return p;
  };
  char* regionA = alloc(25600L*1024*2);   // x1 (enc) -> dec (decoder/head)
  char* regionB = alloc(25600L*1024*2);   // inpb (18MB) -> x2 -> feat chunks
  ushort_t* preFc = (ushort_t*)alloc(3200L*2048*2);  // pre-gate chunk, fwd
  ushort_t* preBc = (ushort_t*)alloc(3200L*2048*2);  // pre-gate chunk, bwd
  ushort_t* zb    = (ushort_t*)alloc(25600L*192*2);
  ushort_t* w_e0f = (ushort_t*)alloc(2048L*352*2);
  ushort_t* w_e0b = (ushort_t*)alloc(2048L*352*2);
  ushort_t* w_e1f = (ushort_t*)alloc(2048L*1024*2);
  ushort_t* w_e1b = (ushort_t*)alloc(2048L*1024*2);
  ushort_t* w_h0f = (ushort_t*)alloc(2048L*512*2);
  ushort_t* w_h0b = (ushort_t*)alloc(2048L*512*2);
  ushort_t* w_h1f = (ushort_t*)alloc(2048L*512*2);
  ushort_t* w_h1b = (ushort_t*)alloc(2048L*512*2);
  ushort_t* w_mu  = (ushort_t*)alloc(256L*1024*2);
  ushort_t* w_sig = (ushort_t*)alloc(256L*1024*2);
  ushort_t* w_dzf = (ushort_t*)alloc(2048L*192*2);
  ushort_t* w_dzb = (ushort_t*)alloc(2048L*192*2);
  ushort_t* BfT   = (ushort_t*)alloc(2048L*1024*2);
  ushort_t* BbT   = (ushort_t*)alloc(2048L*1024*2);
  ushort_t* w_feat= (ushort_t*)alloc(2048L*1024*2);
  ushort_t* w_scr = (ushort_t*)alloc(384L*2048*2);
  float* bdF  = (float*)alloc(2048*4);
  float* bdB  = (float*)alloc(2048*4);
  float* cEF  = (float*)alloc(32L*512*4);
  float* cEB  = (float*)alloc(32L*512*4);
  float* cDF  = (float*)alloc(32L*512*4);
  float* cDB  = (float*)alloc(32L*512*4);
  ushort_t* zerob = (ushort_t*)alloc(32L*1024*2);
  ushort_t* pinit = (ushort_t*)alloc(32L*1024*2);

  ushort_t* x1    = (ushort_t*)regionA;   // [25600][1024]
  ushort_t* dec   = (ushort_t*)regionA;   // alias: written only after x1's last read
  ushort_t* inpb  = (ushort_t*)regionB;   // [25600][352], dead after layer-0 pre chunks
  ushort_t* x2    = (ushort_t*)regionB;   // [25600][1024], written in layer-1 (after inpb dead)
  ushort_t* featc = (ushort_t*)regionB;   // [3200][2048] head chunk (after x2 dead)

  if (ws_size < off){   // not enough scratch: bail with clean zeros
    hipMemsetAsync(d_out, 0, (size_t)out_size*4, stream);
    return;
  }

  auto CVT=[&](const float* s, ushort_t* d, int Rs, int Cs, int c0_, int Cc, int Cd, int Rd){
    long tot = (long)Rd*Cd;
    int blocks = (int)((tot + 255)/256);
    cvt_pad<<<blocks, 256, 0, stream>>>(s, d, Rs, Cs, c0_, Cc, Cd, tot);
  };
  auto GEMM=[&](const ushort_t* A, int lda, const ushort_t* B, int ldb, const float* bias,
                int K, int Nreal, int mode, int ldc, float* oF, ushort_t* oB, int nt, int mt){
    gemm_bt<<<dim3(nt,mt), 256, 0, stream>>>(A, lda, B, ldb, bias, K, Nreal, mode, ldc, oF, oB);
  };

  // ---------------- weight/input conversions ----------------
  CVT(inp,     inpb,  25600, 321, 0, 321, 352, 25600);
  CVT(e0f_Wih, w_e0f, 2048, 321, 0, 321, 352, 2048);
  CVT(e0b_Wih, w_e0b, 2048, 321, 0, 321, 352, 2048);
  CVT(e1f_Wih, w_e1f, 2048, 1024, 0, 1024, 1024, 2048);
  CVT(e1b_Wih, w_e1b, 2048, 1024, 0, 1024, 1024, 2048);
  CVT(e0f_Whh, w_h0f, 2048, 512, 0, 512, 512, 2048);
  CVT(e0b_Whh, w_h0b, 2048, 512, 0, 512, 512, 2048);
  CVT(e1f_Whh, w_h1f, 2048, 512, 0, 512, 512, 2048);
  CVT(e1b_Whh, w_h1b, 2048, 512, 0, 512, 512, 2048);
  CVT(mu_W,    w_mu,  192, 1024, 0, 1024, 1024, 256);
  CVT(sig_W,   w_sig, 192, 1024, 0, 1024, 1024, 256);
  CVT(df_Wih,  w_dzf, 2048, 256, 0, 192, 192, 2048);
  CVT(db_Wih,  w_dzb, 2048, 256, 0, 192, 192, 2048);
  CVT(feat_W,  w_feat,2048, 1024, 0, 1024, 1024, 2048);
  CVT(score_W, w_scr, 321, 2048, 0, 2048, 2048, 384);
  fold_w<<<dim3(4,2048), 256, 0, stream>>>(df_Wih, df_Whh, ctx_W, BfT, 0);
  fold_w<<<dim3(4,2048), 256, 0, stream>>>(db_Wih, db_Whh, ctx_W, BbT, 512);
  fold_b<<<8, 256, 0, stream>>>(df_b, df_Wih, ctx_b, bdF);
  fold_b<<<8, 256, 0, stream>>>(db_b, db_Wih, ctx_b, bdB);
  hipMemsetAsync(zerob, 0, 32L*1024*2, stream);
  hipMemsetAsync(cEF, 0, 32L*512*4, stream);
  hipMemsetAsync(cEB, 0, 32L*512*4, stream);
  dec_init<<<128, 256, 0, stream>>>(h0, c0, pinit, cDF, cDB);

  const int C = 100;            // steps per chunk
  const int RPC = C*32;         // rows per chunk = 3200 (25 m-tiles)

  // ---------------- encoder layer 0 (chunked pre + steps) ----------------
  for (int c = 0; c < 8; c++){
    int f0 = c*C;                     // fwd timesteps [f0, f0+C)
    int b0 = 800 - (c+1)*C;           // bwd timesteps [b0, b0+C), tb descending in step order
    GEMM(inpb + (long)f0*32*352, 352, w_e0f, 352, e0f_b, 352, 2048, 1, 2048, nullptr, preFc, 16, 25);
    GEMM(inpb + (long)b0*32*352, 352, w_e0b, 352, e0b_b, 352, 2048, 1, 2048, nullptr, preBc, 16, 25);
    for (int j = 0; j < C; j++){
      int s = f0 + j, tf = s, tb = 799 - s;
      const ushort_t* Aff = s ? x1 + (long)(tf-1)*32768        : zerob;
      const ushort_t* Abb = s ? x1 + (long)(tb+1)*32768 + 512  : zerob;
      lstm_step<512><<<256, 256, 0, stream>>>(
        Aff, Abb, preFc + (long)j*65536, preBc + (long)(C-1-j)*65536,
        w_h0f, w_h0b, cEF, cEB,
        x1 + (long)tf*32768, x1 + (long)tb*32768 + 512);
    }
  }

  // ---------------- encoder layer 1 (chunked) ----------------
  hipMemsetAsync(cEF, 0, 32L*512*4, stream);
  hipMemsetAsync(cEB, 0, 32L*512*4, stream);
  for (int c = 0; c < 8; c++){
    int f0 = c*C;
    int b0 = 800 - (c+1)*C;
    GEMM(x1 + (long)f0*32768, 1024, w_e1f, 1024, e1f_b, 1024, 2048, 1, 2048, nullptr, preFc, 16, 25);
    GEMM(x1 + (long)b0*32768, 1024, w_e1b, 1024, e1b_b, 1024, 2048, 1, 2048, nullptr, preBc, 16, 25);
    for (int j = 0; j < C; j++){
      int s = f0 + j, tf = s, tb = 799 - s;
      const ushort_t* Aff = s ? x2 + (long)(tf-1)*32768        : zerob;
      const ushort_t* Abb = s ? x2 + (long)(tb+1)*32768 + 512  : zerob;
      lstm_step<512><<<256, 256, 0, stream>>>(
        Aff, Abb, preFc + (long)j*65536, preBc + (long)(C-1-j)*65536,
        w_h1f, w_h1b, cEF, cEB,
        x2 + (long)tf*32768, x2 + (long)tb*32768 + 512);
    }
  }

  // ---------------- latent heads + z ----------------
  GEMM(x2, 1024, w_mu,  1024, mu_b,  1024, 192, 3, 0, dout + MU_OFF, nullptr, 2, 200);
  GEMM(x2, 1024, w_sig, 1024, sig_b, 1024, 192, 3, 0, dout + LV_OFF, nullptr, 2, 200);
  z_make<<<(int)((4915200 + 255)/256), 256, 0, stream>>>(dout + MU_OFF, dout + LV_OFF, noise, zb);

  // ---------------- decoder (chunked pre from z; both dirs same time order) ----------------
  for (int c = 0; c < 8; c++){
    int f0 = c*C;
    GEMM(zb + (long)f0*32*192, 192, w_dzf, 192, bdF, 192, 2048, 1, 2048, nullptr, preFc, 16, 25);
    GEMM(zb + (long)f0*32*192, 192, w_dzb, 192, bdB, 192, 2048, 1, 2048, nullptr, preBc, 16, 25);
    for (int j = 0; j < C; j++){
      int t = f0 + j;
      const ushort_t* Ap = t ? dec + (long)(t-1)*32768 : pinit;
      lstm_step<1024><<<256, 256, 0, stream>>>(
        Ap, Ap, preFc + (long)j*65536, preBc + (long)j*65536,
        BfT, BbT, cDF, cDB,
        dec + (long)t*32768, dec + (long)t*32768 + 512);
    }
  }

  // ---------------- output head (chunked rows; featc aliases regionB) ----------------
  for (int c = 0; c < 8; c++){
    long r0 = (long)c*RPC;
    GEMM(dec + r0*1024, 1024, w_feat, 1024, feat_b, 1024, 2048, 2, 2048, nullptr, featc, 16, 25);
    GEMM(featc, 2048, w_scr, 2048, score_b, 2048, 321, 0, 321, dout + Y_OFF + r0*321, nullptr, 3, 25);
  }
  fill1<<<100, 256, 0, stream>>>(dout + MK_OFF, 25600);
}

// Round 15
// 13866.611 us; speedup vs baseline: 68.4315x; 1.0437x over previous
//
#include <hip/hip_runtime.h>

typedef unsigned short ushort_t;
typedef __attribute__((ext_vector_type(4))) float f4;
typedef __attribute__((ext_vector_type(4))) int   i4;

__device__ __forceinline__ float b2f(ushort_t u){
  union { unsigned int i; float f; } v; v.i = ((unsigned int)u) << 16; return v.f;
}
__device__ __forceinline__ ushort_t f2b(float f){
  union { float f; unsigned int i; } v; v.f = f;
  unsigned int u = v.i;
  return (ushort_t)((u + 0x7fffu + ((u >> 16) & 1u)) >> 16);
}
__device__ __forceinline__ float sigm(float x){ return 1.f/(1.f + __expf(-x)); }

// ---------------- fp32 -> bf16 convert with optional col-slice and zero padding ----------------
__global__ void cvt_pad(const float* __restrict__ src, ushort_t* __restrict__ dst,
                        int Rsrc, int Csrc, int col0, int Ccopy, int Cdst, long total){
  long i = (long)blockIdx.x*256 + threadIdx.x;
  if (i >= total) return;
  int r = (int)(i / Cdst), c = (int)(i % Cdst);
  float v = 0.f;
  if (r < Rsrc && c < Ccopy) v = src[(long)r*Csrc + col0 + c];
  dst[i] = f2b(v);
}

// ---------------- decoder weight fold ----------------
__global__ void fold_w(const float* __restrict__ Wih, const float* __restrict__ Whh,
                       const float* __restrict__ ctxW, ushort_t* __restrict__ out, int poff){
  int p = blockIdx.x*256 + threadIdx.x;     // 0..1023
  int q = blockIdx.y;                       // 0..2047
  if (p >= 1024) return;
  float s = 0.f;
  #pragma unroll 8
  for (int e=0;e<64;e++) s += Wih[q*256 + 192 + e] * ctxW[e*1024 + p];
  if (p >= poff && p < poff + 512) s += Whh[q*512 + (p - poff)];
  out[(long)q*1024 + p] = f2b(s);
}

__global__ void fold_b(const float* __restrict__ b, const float* __restrict__ Wih,
                       const float* __restrict__ ctxb, float* __restrict__ out){
  int q = blockIdx.x*256 + threadIdx.x;
  if (q >= 2048) return;
  float s = b[q];
  #pragma unroll 8
  for (int e=0;e<64;e++) s += ctxb[e]*Wih[q*256 + 192 + e];
  out[q] = s;
}

// ---------------- z = mu + exp(0.5*lv)*noise ; reshape [K,S,N,E] -> [S*N, K*E] bf16 ----------------
__global__ void z_make(const float* __restrict__ mu, const float* __restrict__ lv,
                       const float* __restrict__ noise, ushort_t* __restrict__ zb){
  long i = (long)blockIdx.x*256 + threadIdx.x;
  if (i >= 3L*800*32*64) return;
  int e = (int)(i & 63); int n = (int)((i>>6) & 31);
  long r = i >> 11; int s = (int)(r % 800); int k = (int)(r / 800);
  float z = mu[i] + __expf(0.5f*lv[i]) * noise[i];
  zb[((long)(s*32 + n))*192 + k*64 + e] = f2b(z);
}

__global__ void dec_init(const float* __restrict__ h0, const float* __restrict__ c0,
                         ushort_t* __restrict__ prev, float* __restrict__ cDF, float* __restrict__ cDB){
  int i = blockIdx.x*256 + threadIdx.x;
  if (i < 32*1024) prev[i] = f2b(h0[i & 1023]);
  if (i < 32*512){ cDF[i] = c0[i & 511]; cDB[i] = c0[512 + (i & 511)]; }
}

__global__ void fill1(float* __restrict__ p, long n){
  long i = (long)blockIdx.x*256 + threadIdx.x;
  if (i < n) p[i] = 1.f;
}

// ---------------- bf16 MFMA GEMM: C[m][n] = sum_k A[m][k]*B[n][k] + bias[n] ----------------
// A: [M][lda] bf16 (M = gridDim.y*128), B: [Ntiles*128][ldb] bf16 (rows zero-padded), K mult of 32.
// mode 0: fp32 C[m*ldc+n]; 1: bf16; 2: tanh->bf16; 3: fp32 mu-scatter (k=n>>6,e=n&63; out[k*1638400+m*64+e])
#define GLD 40
__global__ __launch_bounds__(256) void gemm_bt(
    const ushort_t* __restrict__ A, int lda,
    const ushort_t* __restrict__ B, int ldb,
    const float* __restrict__ bias, int K, int Nreal, int mode, int ldc,
    float* __restrict__ outF, ushort_t* __restrict__ outB)
{
  __shared__ ushort_t Al[128*GLD];
  __shared__ ushort_t Bl[128*GLD];
  int tid = threadIdx.x;
  int m0 = blockIdx.y * 128;
  int n0 = blockIdx.x * 128;
  int l = tid & 63, w = tid >> 6;
  int wm = w & 1, wn = w >> 1;
  int srow = tid >> 2;       // 0..63
  int scg  = tid & 3;        // 0..3 (16B chunks of the 64B-wide K-tile rows)

  f4 acc[4][4];
  #pragma unroll
  for (int i=0;i<4;i++)
    #pragma unroll
    for (int j=0;j<4;j++) acc[i][j] = (f4){0.f,0.f,0.f,0.f};

  i4 pa0, pa1, pb0, pb1;
  {
    long ab = (long)(m0 + srow)*lda + scg*8;
    pa0 = *(const i4*)&A[ab];
    pa1 = *(const i4*)&A[ab + 64L*lda];
    long bb = (long)(n0 + srow)*ldb + scg*8;
    pb0 = *(const i4*)&B[bb];
    pb1 = *(const i4*)&B[bb + 64L*ldb];
  }
  for (int k0 = 0; k0 < K; k0 += 32){
    __syncthreads();
    *(i4*)&Al[srow*GLD + scg*8]      = pa0;
    *(i4*)&Al[(srow+64)*GLD + scg*8] = pa1;
    *(i4*)&Bl[srow*GLD + scg*8]      = pb0;
    *(i4*)&Bl[(srow+64)*GLD + scg*8] = pb1;
    __syncthreads();
    if (k0 + 32 < K){
      long ab = (long)(m0 + srow)*lda + k0 + 32 + scg*8;
      pa0 = *(const i4*)&A[ab];
      pa1 = *(const i4*)&A[ab + 64L*lda];
      long bb = (long)(n0 + srow)*ldb + k0 + 32 + scg*8;
      pb0 = *(const i4*)&B[bb];
      pb1 = *(const i4*)&B[bb + 64L*ldb];
    }
    int kg = (l>>4)*8;
    i4 av[4], bv[4];
    #pragma unroll
    for (int r=0;r<4;r++)
      av[r] = *(const i4*)&Al[(wm*64 + r*16 + (l&15))*GLD + kg];
    #pragma unroll
    for (int r=0;r<4;r++)
      bv[r] = *(const i4*)&Bl[(wn*64 + r*16 + (l&15))*GLD + kg];
    #pragma unroll
    for (int i=0;i<4;i++)
      #pragma unroll
      for (int j=0;j<4;j++)
        asm volatile("v_mfma_f32_16x16x32_bf16 %0, %1, %2, %0"
                     : "+v"(acc[i][j]) : "v"(av[i]), "v"(bv[j]));
  }
  asm volatile("s_nop 7\n\ts_nop 7\n\ts_nop 7");
  int row_l = (l>>4)*4, col_l = l&15;
  #pragma unroll
  for (int i=0;i<4;i++){
    #pragma unroll
    for (int j=0;j<4;j++){
      int n = n0 + wn*64 + j*16 + col_l;
      if (n >= Nreal) continue;
      float bb = bias[n];
      #pragma unroll
      for (int r=0;r<4;r++){
        int m = m0 + wm*64 + i*16 + row_l + r;
        float v = acc[i][j][r] + bb;
        if (mode == 0){
          outF[(long)m*ldc + n] = v;
        } else if (mode == 1){
          outB[(long)m*ldc + n] = f2b(v);
        } else if (mode == 2){
          outB[(long)m*ldc + n] = f2b(tanhf(v));
        } else {
          outF[(long)(n>>6)*1638400 + (long)m*64 + (n&63)] = v;
        }
      }
    }
  }
}

// ---------------- fused LSTM step, all-CU version ----------------
// 256 blocks: dir = bx>>7, 4 hidden units u0 = (bx&127)*4 (all 4 gates).
// Waves split K into 4 slices; partial C[32x16] summed via LDS.
// pre/c loads hoisted to kernel entry (latency overlaps MFMA phase; the compiler
// cannot hoist them across __syncthreads itself).
template<int KA>
__global__ __launch_bounds__(256) void lstm_step(
    const ushort_t* __restrict__ Af, const ushort_t* __restrict__ Ab,  // prev h, row stride 1024
    const ushort_t* __restrict__ preF, const ushort_t* __restrict__ preB, // [32][2048] chunk rows
    const ushort_t* __restrict__ Wf, const ushort_t* __restrict__ Wb,  // [2048][KA], row = g*512+j
    float* __restrict__ cF, float* __restrict__ cB,                    // [32][512]
    ushort_t* __restrict__ outF, ushort_t* __restrict__ outB)          // row stride 1024
{
  __shared__ float gl[4][32][17];
  int tid = threadIdx.x;
  int dir = blockIdx.x >> 7;
  int u0  = (blockIdx.x & 127) << 2;   // 4 hidden units
  const ushort_t* A   = dir ? Ab   : Af;
  const ushort_t* pre = dir ? preB : preF;
  const ushort_t* W   = dir ? Wb   : Wf;
  float* c            = dir ? cB   : cF;
  ushort_t* out       = dir ? outB : outF;

  // ---- hoisted epilogue loads (barrier-independent; owned per-thread) ----
  int n_e = tid >> 2, ju = tid & 3;
  int j_e = u0 + ju;
  float pre_i = 0.f, pre_f = 0.f, pre_g = 0.f, pre_o = 0.f, cv = 0.f;
  if (tid < 128){
    pre_i = b2f(pre[n_e*2048 + j_e]);
    pre_f = b2f(pre[n_e*2048 + 512 + j_e]);
    pre_g = b2f(pre[n_e*2048 + 1024 + j_e]);
    pre_o = b2f(pre[n_e*2048 + 1536 + j_e]);
    cv    = c[n_e*512 + j_e];
  }

  int l = tid & 63, w = tid >> 6;
  int col = l & 15;                    // out col: gate g = col>>2, unit u0+(col&3)
  constexpr int KW = KA/4;             // per-wave K slice
  int kgw = w*KW + (l>>4)*8;
  int wrow = (col>>2)*512 + u0 + (col&3);
  const ushort_t* Wr  = &W[(long)wrow*KA + kgw];
  const ushort_t* Ar0 = &A[col*1024 + kgw];
  const ushort_t* Ar1 = &A[(col+16)*1024 + kgw];
  f4 acc0 = (f4){0.f,0.f,0.f,0.f}, acc1 = (f4){0.f,0.f,0.f,0.f};
  #pragma unroll
  for (int k0=0;k0<KW;k0+=32){
    i4 b  = *(const i4*)&Wr[k0];
    i4 a0 = *(const i4*)&Ar0[k0];
    i4 a1 = *(const i4*)&Ar1[k0];
    asm volatile("v_mfma_f32_16x16x32_bf16 %0, %1, %2, %0" : "+v"(acc0) : "v"(a0), "v"(b));
    asm volatile("v_mfma_f32_16x16x32_bf16 %0, %1, %2, %0" : "+v"(acc1) : "v"(a1), "v"(b));
  }
  asm volatile("s_nop 7\n\ts_nop 7\n\ts_nop 7");
  int rl = (l>>4)*4;
  #pragma unroll
  for (int r=0;r<4;r++){
    gl[w][rl + r][col]      = acc0[r];
    gl[w][rl + r + 16][col] = acc1[r];
  }
  __syncthreads();
  if (tid < 128){
    float gs[4];
    #pragma unroll
    for (int g=0; g<4; g++){
      int cc = g*4 + ju;
      gs[g] = gl[0][n_e][cc] + gl[1][n_e][cc] + gl[2][n_e][cc] + gl[3][n_e][cc];
    }
    float gi = gs[0] + pre_i;
    float gf = gs[1] + pre_f;
    float gg = gs[2] + pre_g;
    float go = gs[3] + pre_o;
    float ii = sigm(gi), ff = sigm(gf), g2 = tanhf(gg), oo = sigm(go);
    float cn = ff*cv + ii*g2;
    c[n_e*512 + j_e] = cn;
    out[n_e*1024 + j_e] = f2b(oo*tanhf(cn));
  }
}

extern "C" void kernel_launch(void* const* d_in, const int* in_sizes, int n_in,
                              void* d_out, int out_size, void* d_ws, size_t ws_size,
                              hipStream_t stream)
{
  const float* inp    = (const float*)d_in[0];
  const float* noise  = (const float*)d_in[1];
  const float* e0f_Wih=(const float*)d_in[2];
  const float* e0f_Whh=(const float*)d_in[3];
  const float* e0f_b  =(const float*)d_in[4];
  const float* e0b_Wih=(const float*)d_in[5];
  const float* e0b_Whh=(const float*)d_in[6];
  const float* e0b_b  =(const float*)d_in[7];
  const float* e1f_Wih=(const float*)d_in[8];
  const float* e1f_Whh=(const float*)d_in[9];
  const float* e1f_b  =(const float*)d_in[10];
  const float* e1b_Wih=(const float*)d_in[11];
  const float* e1b_Whh=(const float*)d_in[12];
  const float* e1b_b  =(const float*)d_in[13];
  const float* df_Wih =(const float*)d_in[14];
  const float* df_Whh =(const float*)d_in[15];
  const float* df_b   =(const float*)d_in[16];
  const float* db_Wih =(const float*)d_in[17];
  const float* db_Whh =(const float*)d_in[18];
  const float* db_b   =(const float*)d_in[19];
  const float* mu_W   =(const float*)d_in[20];
  const float* mu_b   =(const float*)d_in[21];
  const float* sig_W  =(const float*)d_in[22];
  const float* sig_b  =(const float*)d_in[23];
  const float* h0     =(const float*)d_in[24];
  const float* c0     =(const float*)d_in[25];
  const float* ctx_W  =(const float*)d_in[26];
  const float* ctx_b  =(const float*)d_in[27];
  const float* feat_W =(const float*)d_in[28];
  const float* feat_b =(const float*)d_in[29];
  const float* score_W=(const float*)d_in[30];
  const float* score_b=(const float*)d_in[31];

  float* dout = (float*)d_out;
  const long Y_OFF  = 0;
  const long MU_OFF = 8217600;
  const long LV_OFF = 13132800;
  const long MK_OFF = 18048000;

  // ---------------- workspace layout (~178 MB with aliasing) ----------------
  char* ws = (char*)d_ws;
  size_t off = 0;
  auto alloc = [&](size_t bytes)->char*{
    char* p = ws + off; off += (bytes + 255) & ~(size_t)255; return p;
  };
  char* regionA = alloc(25600L*1024*2);   // x1 (enc) -> dec (decoder/head)
  char* regionB = alloc(25600L*1024*2);   // inpb (18MB) -> x2 -> feat chunks
  ushort_t* preFc = (ushort_t*)alloc(3200L*2048*2);  // pre-gate chunk, fwd
  ushort_t* preBc = (ushort_t*)alloc(3200L*2048*2);  // pre-gate chunk, bwd
  ushort_t* zb    = (ushort_t*)alloc(25600L*192*2);
  ushort_t* w_e0f = (ushort_t*)alloc(2048L*352*2);
  ushort_t* w_e0b = (ushort_t*)alloc(2048L*352*2);
  ushort_t* w_e1f = (ushort_t*)alloc(2048L*1024*2);
  ushort_t* w_e1b = (ushort_t*)alloc(2048L*1024*2);
  ushort_t* w_h0f = (ushort_t*)alloc(2048L*512*2);
  ushort_t* w_h0b = (ushort_t*)alloc(2048L*512*2);
  ushort_t* w_h1f = (ushort_t*)alloc(2048L*512*2);
  ushort_t* w_h1b = (ushort_t*)alloc(2048L*512*2);
  ushort_t* w_mu  = (ushort_t*)alloc(256L*1024*2);
  ushort_t* w_sig = (ushort_t*)alloc(256L*1024*2);
  ushort_t* w_dzf = (ushort_t*)alloc(2048L*192*2);
  ushort_t* w_dzb = (ushort_t*)alloc(2048L*192*2);
  ushort_t* BfT   = (ushort_t*)alloc(2048L*1024*2);
  ushort_t* BbT   = (ushort_t*)alloc(2048L*1024*2);
  ushort_t* w_feat= (ushort_t*)alloc(2048L*1024*2);
  ushort_t* w_scr = (ushort_t*)alloc(384L*2048*2);
  float* bdF  = (float*)alloc(2048*4);
  float* bdB  = (float*)alloc(2048*4);
  float* cEF  = (float*)alloc(32L*512*4);
  float* cEB  = (float*)alloc(32L*512*4);
  float* cDF  = (float*)alloc(32L*512*4);
  float* cDB  = (float*)alloc(32L*512*4);
  ushort_t* zerob = (ushort_t*)alloc(32L*1024*2);
  ushort_t* pinit = (ushort_t*)alloc(32L*1024*2);

  ushort_t* x1    = (ushort_t*)regionA;   // [25600][1024]
  ushort_t* dec   = (ushort_t*)regionA;   // alias: written only after x1's last read
  ushort_t* inpb  = (ushort_t*)regionB;   // [25600][352], dead after layer-0 pre chunks
  ushort_t* x2    = (ushort_t*)regionB;   // [25600][1024], written in layer-1 (after inpb dead)
  ushort_t* featc = (ushort_t*)regionB;   // [3200][2048] head chunk (after x2 dead)

  if (ws_size < off){   // not enough scratch: bail with clean zeros
    hipMemsetAsync(d_out, 0, (size_t)out_size*4, stream);
    return;
  }

  auto CVT=[&](const float* s, ushort_t* d, int Rs, int Cs, int c0_, int Cc, int Cd, int Rd){
    long tot = (long)Rd*Cd;
    int blocks = (int)((tot + 255)/256);
    cvt_pad<<<blocks, 256, 0, stream>>>(s, d, Rs, Cs, c0_, Cc, Cd, tot);
  };
  auto GEMM=[&](const ushort_t* A, int lda, const ushort_t* B, int ldb, const float* bias,
                int K, int Nreal, int mode, int ldc, float* oF, ushort_t* oB, int nt, int mt){
    gemm_bt<<<dim3(nt,mt), 256, 0, stream>>>(A, lda, B, ldb, bias, K, Nreal, mode, ldc, oF, oB);
  };

  // ---------------- weight/input conversions ----------------
  CVT(inp,     inpb,  25600, 321, 0, 321, 352, 25600);
  CVT(e0f_Wih, w_e0f, 2048, 321, 0, 321, 352, 2048);
  CVT(e0b_Wih, w_e0b, 2048, 321, 0, 321, 352, 2048);
  CVT(e1f_Wih, w_e1f, 2048, 1024, 0, 1024, 1024, 2048);
  CVT(e1b_Wih, w_e1b, 2048, 1024, 0, 1024, 1024, 2048);
  CVT(e0f_Whh, w_h0f, 2048, 512, 0, 512, 512, 2048);
  CVT(e0b_Whh, w_h0b, 2048, 512, 0, 512, 512, 2048);
  CVT(e1f_Whh, w_h1f, 2048, 512, 0, 512, 512, 2048);
  CVT(e1b_Whh, w_h1b, 2048, 512, 0, 512, 512, 2048);
  CVT(mu_W,    w_mu,  192, 1024, 0, 1024, 1024, 256);
  CVT(sig_W,   w_sig, 192, 1024, 0, 1024, 1024, 256);
  CVT(df_Wih,  w_dzf, 2048, 256, 0, 192, 192, 2048);
  CVT(db_Wih,  w_dzb, 2048, 256, 0, 192, 192, 2048);
  CVT(feat_W,  w_feat,2048, 1024, 0, 1024, 1024, 2048);
  CVT(score_W, w_scr, 321, 2048, 0, 2048, 2048, 384);
  fold_w<<<dim3(4,2048), 256, 0, stream>>>(df_Wih, df_Whh, ctx_W, BfT, 0);
  fold_w<<<dim3(4,2048), 256, 0, stream>>>(db_Wih, db_Whh, ctx_W, BbT, 512);
  fold_b<<<8, 256, 0, stream>>>(df_b, df_Wih, ctx_b, bdF);
  fold_b<<<8, 256, 0, stream>>>(db_b, db_Wih, ctx_b, bdB);
  hipMemsetAsync(zerob, 0, 32L*1024*2, stream);
  hipMemsetAsync(cEF, 0, 32L*512*4, stream);
  hipMemsetAsync(cEB, 0, 32L*512*4, stream);
  dec_init<<<128, 256, 0, stream>>>(h0, c0, pinit, cDF, cDB);

  const int C = 100;            // steps per chunk
  const int RPC = C*32;         // rows per chunk = 3200 (25 m-tiles)

  // ---------------- encoder layer 0 (chunked pre + steps) ----------------
  for (int c = 0; c < 8; c++){
    int f0 = c*C;                     // fwd timesteps [f0, f0+C)
    int b0 = 800 - (c+1)*C;           // bwd timesteps [b0, b0+C), tb descending in step order
    GEMM(inpb + (long)f0*32*352, 352, w_e0f, 352, e0f_b, 352, 2048, 1, 2048, nullptr, preFc, 16, 25);
    GEMM(inpb + (long)b0*32*352, 352, w_e0b, 352, e0b_b, 352, 2048, 1, 2048, nullptr, preBc, 16, 25);
    for (int j = 0; j < C; j++){
      int s = f0 + j, tf = s, tb = 799 - s;
      const ushort_t* Aff = s ? x1 + (long)(tf-1)*32768        : zerob;
      const ushort_t* Abb = s ? x1 + (long)(tb+1)*32768 + 512  : zerob;
      lstm_step<512><<<256, 256, 0, stream>>>(
        Aff, Abb, preFc + (long)j*65536, preBc + (long)(C-1-j)*65536,
        w_h0f, w_h0b, cEF, cEB,
        x1 + (long)tf*32768, x1 + (long)tb*32768 + 512);
    }
  }

  // ---------------- encoder layer 1 (chunked) ----------------
  hipMemsetAsync(cEF, 0, 32L*512*4, stream);
  hipMemsetAsync(cEB, 0, 32L*512*4, stream);
  for (int c = 0; c < 8; c++){
    int f0 = c*C;
    int b0 = 800 - (c+1)*C;
    GEMM(x1 + (long)f0*32768, 1024, w_e1f, 1024, e1f_b, 1024, 2048, 1, 2048, nullptr, preFc, 16, 25);
    GEMM(x1 + (long)b0*32768, 1024, w_e1b, 1024, e1b_b, 1024, 2048, 1, 2048, nullptr, preBc, 16, 25);
    for (int j = 0; j < C; j++){
      int s = f0 + j, tf = s, tb = 799 - s;
      const ushort_t* Aff = s ? x2 + (long)(tf-1)*32768        : zerob;
      const ushort_t* Abb = s ? x2 + (long)(tb+1)*32768 + 512  : zerob;
      lstm_step<512><<<256, 256, 0, stream>>>(
        Aff, Abb, preFc + (long)j*65536, preBc + (long)(C-1-j)*65536,
        w_h1f, w_h1b, cEF, cEB,
        x2 + (long)tf*32768, x2 + (long)tb*32768 + 512);
    }
  }

  // ---------------- latent heads + z ----------------
  GEMM(x2, 1024, w_mu,  1024, mu_b,  1024, 192, 3, 0, dout + MU_OFF, nullptr, 2, 200);
  GEMM(x2, 1024, w_sig, 1024, sig_b, 1024, 192, 3, 0, dout + LV_OFF, nullptr, 2, 200);
  z_make<<<(int)((4915200 + 255)/256), 256, 0, stream>>>(dout + MU_OFF, dout + LV_OFF, noise, zb);

  // ---------------- decoder (chunked pre from z; both dirs same time order) ----------------
  for (int c = 0; c < 8; c++){
    int f0 = c*C;
    GEMM(zb + (long)f0*32*192, 192, w_dzf, 192, bdF, 192, 2048, 1, 2048, nullptr, preFc, 16, 25);
    GEMM(zb + (long)f0*32*192, 192, w_dzb, 192, bdB, 192, 2048, 1, 2048, nullptr, preBc, 16, 25);
    for (int j = 0; j < C; j++){
      int t = f0 + j;
      const ushort_t* Ap = t ? dec + (long)(t-1)*32768 : pinit;
      lstm_step<1024><<<256, 256, 0, stream>>>(
        Ap, Ap, preFc + (long)j*65536, preBc + (long)j*65536,
        BfT, BbT, cDF, cDB,
        dec + (long)t*32768, dec + (long)t*32768 + 512);
    }
  }

  // ---------------- output head (chunked rows; featc aliases regionB) ----------------
  for (int c = 0; c < 8; c++){
    long r0 = (long)c*RPC;
    GEMM(dec + r0*1024, 1024, w_feat, 1024, feat_b, 1024, 2048, 2, 2048, nullptr, featc, 16, 25);
    GEMM(featc, 2048, w_scr, 2048, score_b, 2048, 321, 0, 321, dout + Y_OFF + r0*321, nullptr, 3, 25);
  }
  fill1<<<100, 256, 0, stream>>>(dout + MK_OFF, 25600);
}

// Round 17
// 13281.926 us; speedup vs baseline: 71.4439x; 1.0440x over previous
//
#include <hip/hip_runtime.h>

typedef unsigned short ushort_t;
typedef __attribute__((ext_vector_type(4))) float f4;
typedef __attribute__((ext_vector_type(4))) int   i4;

__device__ __forceinline__ float b2f(ushort_t u){
  union { unsigned int i; float f; } v; v.i = ((unsigned int)u) << 16; return v.f;
}
__device__ __forceinline__ ushort_t f2b(float f){
  union { float f; unsigned int i; } v; v.f = f;
  unsigned int u = v.i;
  return (ushort_t)((u + 0x7fffu + ((u >> 16) & 1u)) >> 16);
}
__device__ __forceinline__ float sigm(float x){ return 1.f/(1.f + __expf(-x)); }

// ---------------- fp32 -> bf16 convert with optional col-slice and zero padding ----------------
__global__ void cvt_pad(const float* __restrict__ src, ushort_t* __restrict__ dst,
                        int Rsrc, int Csrc, int col0, int Ccopy, int Cdst, long total){
  long i = (long)blockIdx.x*256 + threadIdx.x;
  if (i >= total) return;
  int r = (int)(i / Cdst), c = (int)(i % Cdst);
  float v = 0.f;
  if (r < Rsrc && c < Ccopy) v = src[(long)r*Csrc + col0 + c];
  dst[i] = f2b(v);
}

// ---------------- decoder weight fold ----------------
__global__ void fold_w(const float* __restrict__ Wih, const float* __restrict__ Whh,
                       const float* __restrict__ ctxW, ushort_t* __restrict__ out, int poff){
  int p = blockIdx.x*256 + threadIdx.x;     // 0..1023
  int q = blockIdx.y;                       // 0..2047
  if (p >= 1024) return;
  float s = 0.f;
  #pragma unroll 8
  for (int e=0;e<64;e++) s += Wih[q*256 + 192 + e] * ctxW[e*1024 + p];
  if (p >= poff && p < poff + 512) s += Whh[q*512 + (p - poff)];
  out[(long)q*1024 + p] = f2b(s);
}

__global__ void fold_b(const float* __restrict__ b, const float* __restrict__ Wih,
                       const float* __restrict__ ctxb, float* __restrict__ out){
  int q = blockIdx.x*256 + threadIdx.x;
  if (q >= 2048) return;
  float s = b[q];
  #pragma unroll 8
  for (int e=0;e<64;e++) s += ctxb[e]*Wih[q*256 + 192 + e];
  out[q] = s;
}

// ---------------- z = mu + exp(0.5*lv)*noise ; reshape [K,S,N,E] -> [S*N, K*E] bf16 ----------------
__global__ void z_make(const float* __restrict__ mu, const float* __restrict__ lv,
                       const float* __restrict__ noise, ushort_t* __restrict__ zb){
  long i = (long)blockIdx.x*256 + threadIdx.x;
  if (i >= 3L*800*32*64) return;
  int e = (int)(i & 63); int n = (int)((i>>6) & 31);
  long r = i >> 11; int s = (int)(r % 800); int k = (int)(r / 800);
  float z = mu[i] + __expf(0.5f*lv[i]) * noise[i];
  zb[((long)(s*32 + n))*192 + k*64 + e] = f2b(z);
}

__global__ void dec_init(const float* __restrict__ h0, const float* __restrict__ c0,
                         ushort_t* __restrict__ prev, float* __restrict__ cDF, float* __restrict__ cDB){
  int i = blockIdx.x*256 + threadIdx.x;
  if (i < 32*1024) prev[i] = f2b(h0[i & 1023]);
  if (i < 32*512){ cDF[i] = c0[i & 511]; cDB[i] = c0[512 + (i & 511)]; }
}

__global__ void fill1(float* __restrict__ p, long n){
  long i = (long)blockIdx.x*256 + threadIdx.x;
  if (i < n) p[i] = 1.f;
}

// ---------------- bf16 MFMA GEMM: C[m][n] = sum_k A[m][k]*B[n][k] + bias[n] ----------------
// A: [M][lda] bf16 (M = gridDim.y*128), B: [Ntiles*128][ldb] bf16 (rows zero-padded), K mult of 32.
// mode 0: fp32 C[m*ldc+n]; 1: bf16; 2: tanh->bf16; 3: fp32 mu-scatter (k=n>>6,e=n&63; out[k*1638400+m*64+e])
#define GLD 40
__global__ __launch_bounds__(256) void gemm_bt(
    const ushort_t* __restrict__ A, int lda,
    const ushort_t* __restrict__ B, int ldb,
    const float* __restrict__ bias, int K, int Nreal, int mode, int ldc,
    float* __restrict__ outF, ushort_t* __restrict__ outB)
{
  __shared__ ushort_t Al[128*GLD];
  __shared__ ushort_t Bl[128*GLD];
  int tid = threadIdx.x;
  int m0 = blockIdx.y * 128;
  int n0 = blockIdx.x * 128;
  int l = tid & 63, w = tid >> 6;
  int wm = w & 1, wn = w >> 1;
  int srow = tid >> 2;       // 0..63
  int scg  = tid & 3;        // 0..3 (16B chunks of the 64B-wide K-tile rows)

  f4 acc[4][4];
  #pragma unroll
  for (int i=0;i<4;i++)
    #pragma unroll
    for (int j=0;j<4;j++) acc[i][j] = (f4){0.f,0.f,0.f,0.f};

  i4 pa0, pa1, pb0, pb1;
  {
    long ab = (long)(m0 + srow)*lda + scg*8;
    pa0 = *(const i4*)&A[ab];
    pa1 = *(const i4*)&A[ab + 64L*lda];
    long bb = (long)(n0 + srow)*ldb + scg*8;
    pb0 = *(const i4*)&B[bb];
    pb1 = *(const i4*)&B[bb + 64L*ldb];
  }
  for (int k0 = 0; k0 < K; k0 += 32){
    __syncthreads();
    *(i4*)&Al[srow*GLD + scg*8]      = pa0;
    *(i4*)&Al[(srow+64)*GLD + scg*8] = pa1;
    *(i4*)&Bl[srow*GLD + scg*8]      = pb0;
    *(i4*)&Bl[(srow+64)*GLD + scg*8] = pb1;
    __syncthreads();
    if (k0 + 32 < K){
      long ab = (long)(m0 + srow)*lda + k0 + 32 + scg*8;
      pa0 = *(const i4*)&A[ab];
      pa1 = *(const i4*)&A[ab + 64L*lda];
      long bb = (long)(n0 + srow)*ldb + k0 + 32 + scg*8;
      pb0 = *(const i4*)&B[bb];
      pb1 = *(const i4*)&B[bb + 64L*ldb];
    }
    int kg = (l>>4)*8;
    i4 av[4], bv[4];
    #pragma unroll
    for (int r=0;r<4;r++)
      av[r] = *(const i4*)&Al[(wm*64 + r*16 + (l&15))*GLD + kg];
    #pragma unroll
    for (int r=0;r<4;r++)
      bv[r] = *(const i4*)&Bl[(wn*64 + r*16 + (l&15))*GLD + kg];
    #pragma unroll
    for (int i=0;i<4;i++)
      #pragma unroll
      for (int j=0;j<4;j++)
        asm volatile("v_mfma_f32_16x16x32_bf16 %0, %1, %2, %0"
                     : "+v"(acc[i][j]) : "v"(av[i]), "v"(bv[j]));
  }
  asm volatile("s_nop 7\n\ts_nop 7\n\ts_nop 7");
  int row_l = (l>>4)*4, col_l = l&15;
  #pragma unroll
  for (int i=0;i<4;i++){
    #pragma unroll
    for (int j=0;j<4;j++){
      int n = n0 + wn*64 + j*16 + col_l;
      if (n >= Nreal) continue;
      float bb = bias[n];
      #pragma unroll
      for (int r=0;r<4;r++){
        int m = m0 + wm*64 + i*16 + row_l + r;
        float v = acc[i][j][r] + bb;
        if (mode == 0){
          outF[(long)m*ldc + n] = v;
        } else if (mode == 1){
          outB[(long)m*ldc + n] = f2b(v);
        } else if (mode == 2){
          outB[(long)m*ldc + n] = f2b(tanhf(v));
        } else {
          outF[(long)(n>>6)*1638400 + (long)m*64 + (n&63)] = v;
        }
      }
    }
  }
}

// ---------------- fused fwd+bwd pre-gate GEMM pair (mode-1, Nreal=2048, ldc=2048) ----------------
// grid dim3(16, 2*mt1): blockIdx.y < mt1 -> problem 1 (fwd), else problem 2 (bwd).
__global__ __launch_bounds__(256) void gemm_pre2(
    const ushort_t* __restrict__ A1, const ushort_t* __restrict__ A2, int lda,
    const ushort_t* __restrict__ B1, const ushort_t* __restrict__ B2, int ldb,
    const float* __restrict__ bias1, const float* __restrict__ bias2, int K,
    ushort_t* __restrict__ out1, ushort_t* __restrict__ out2, int mt1)
{
  __shared__ ushort_t Al[128*GLD];
  __shared__ ushort_t Bl[128*GLD];
  int by = blockIdx.y;
  int sel = by >= mt1;
  const ushort_t* A   = sel ? A2 : A1;
  const ushort_t* B   = sel ? B2 : B1;
  const float* bias   = sel ? bias2 : bias1;
  ushort_t* outB      = sel ? out2 : out1;
  int m0 = (by - (sel ? mt1 : 0)) * 128;
  int n0 = blockIdx.x * 128;
  int tid = threadIdx.x;
  int l = tid & 63, w = tid >> 6;
  int wm = w & 1, wn = w >> 1;
  int srow = tid >> 2;
  int scg  = tid & 3;

  f4 acc[4][4];
  #pragma unroll
  for (int i=0;i<4;i++)
    #pragma unroll
    for (int j=0;j<4;j++) acc[i][j] = (f4){0.f,0.f,0.f,0.f};

  i4 pa0, pa1, pb0, pb1;
  {
    long ab = (long)(m0 + srow)*lda + scg*8;
    pa0 = *(const i4*)&A[ab];
    pa1 = *(const i4*)&A[ab + 64L*lda];
    long bb = (long)(n0 + srow)*ldb + scg*8;
    pb0 = *(const i4*)&B[bb];
    pb1 = *(const i4*)&B[bb + 64L*ldb];
  }
  for (int k0 = 0; k0 < K; k0 += 32){
    __syncthreads();
    *(i4*)&Al[srow*GLD + scg*8]      = pa0;
    *(i4*)&Al[(srow+64)*GLD + scg*8] = pa1;
    *(i4*)&Bl[srow*GLD + scg*8]      = pb0;
    *(i4*)&Bl[(srow+64)*GLD + scg*8] = pb1;
    __syncthreads();
    if (k0 + 32 < K){
      long ab = (long)(m0 + srow)*lda + k0 + 32 + scg*8;
      pa0 = *(const i4*)&A[ab];
      pa1 = *(const i4*)&A[ab + 64L*lda];
      long bb = (long)(n0 + srow)*ldb + k0 + 32 + scg*8;
      pb0 = *(const i4*)&B[bb];
      pb1 = *(const i4*)&B[bb + 64L*ldb];
    }
    int kg = (l>>4)*8;
    i4 av[4], bv[4];
    #pragma unroll
    for (int r=0;r<4;r++)
      av[r] = *(const i4*)&Al[(wm*64 + r*16 + (l&15))*GLD + kg];
    #pragma unroll
    for (int r=0;r<4;r++)
      bv[r] = *(const i4*)&Bl[(wn*64 + r*16 + (l&15))*GLD + kg];
    #pragma unroll
    for (int i=0;i<4;i++)
      #pragma unroll
      for (int j=0;j<4;j++)
        asm volatile("v_mfma_f32_16x16x32_bf16 %0, %1, %2, %0"
                     : "+v"(acc[i][j]) : "v"(av[i]), "v"(bv[j]));
  }
  asm volatile("s_nop 7\n\ts_nop 7\n\ts_nop 7");
  int row_l = (l>>4)*4, col_l = l&15;
  #pragma unroll
  for (int i=0;i<4;i++){
    #pragma unroll
    for (int j=0;j<4;j++){
      int n = n0 + wn*64 + j*16 + col_l;
      float bb = bias[n];
      #pragma unroll
      for (int r=0;r<4;r++){
        int m = m0 + wm*64 + i*16 + row_l + r;
        outB[(long)m*2048 + n] = f2b(acc[i][j][r] + bb);
      }
    }
  }
}

// ---------------- fused LSTM step, all-CU version (round-15 verified) ----------------
// 256 blocks: dir = bx>>7, 4 hidden units u0 = (bx&127)*4 (all 4 gates).
// Waves split K into 4 slices; partial C[32x16] summed via LDS.
// pre/c loads hoisted to kernel entry (latency overlaps MFMA phase).
template<int KA>
__global__ __launch_bounds__(256) void lstm_step(
    const ushort_t* __restrict__ Af, const ushort_t* __restrict__ Ab,  // prev h, row stride 1024
    const ushort_t* __restrict__ preF, const ushort_t* __restrict__ preB, // [32][2048] chunk rows
    const ushort_t* __restrict__ Wf, const ushort_t* __restrict__ Wb,  // [2048][KA], row = g*512+j
    float* __restrict__ cF, float* __restrict__ cB,                    // [32][512]
    ushort_t* __restrict__ outF, ushort_t* __restrict__ outB)          // row stride 1024
{
  __shared__ float gl[4][32][17];
  int tid = threadIdx.x;
  int dir = blockIdx.x >> 7;
  int u0  = (blockIdx.x & 127) << 2;   // 4 hidden units
  const ushort_t* A   = dir ? Ab   : Af;
  const ushort_t* pre = dir ? preB : preF;
  const ushort_t* W   = dir ? Wb   : Wf;
  float* c            = dir ? cB   : cF;
  ushort_t* out       = dir ? outB : outF;

  // ---- hoisted epilogue loads (barrier-independent; owned per-thread) ----
  int n_e = tid >> 2, ju = tid & 3;
  int j_e = u0 + ju;
  float pre_i = 0.f, pre_f = 0.f, pre_g = 0.f, pre_o = 0.f, cv = 0.f;
  if (tid < 128){
    pre_i = b2f(pre[n_e*2048 + j_e]);
    pre_f = b2f(pre[n_e*2048 + 512 + j_e]);
    pre_g = b2f(pre[n_e*2048 + 1024 + j_e]);
    pre_o = b2f(pre[n_e*2048 + 1536 + j_e]);
    cv    = c[n_e*512 + j_e];
  }

  int l = tid & 63, w = tid >> 6;
  int col = l & 15;                    // out col: gate g = col>>2, unit u0+(col&3)
  constexpr int KW = KA/4;             // per-wave K slice
  int kgw = w*KW + (l>>4)*8;
  int wrow = (col>>2)*512 + u0 + (col&3);
  const ushort_t* Wr  = &W[(long)wrow*KA + kgw];
  const ushort_t* Ar0 = &A[col*1024 + kgw];
  const ushort_t* Ar1 = &A[(col+16)*1024 + kgw];
  f4 acc0 = (f4){0.f,0.f,0.f,0.f}, acc1 = (f4){0.f,0.f,0.f,0.f};
  #pragma unroll
  for (int k0=0;k0<KW;k0+=32){
    i4 b  = *(const i4*)&Wr[k0];
    i4 a0 = *(const i4*)&Ar0[k0];
    i4 a1 = *(const i4*)&Ar1[k0];
    asm volatile("v_mfma_f32_16x16x32_bf16 %0, %1, %2, %0" : "+v"(acc0) : "v"(a0), "v"(b));
    asm volatile("v_mfma_f32_16x16x32_bf16 %0, %1, %2, %0" : "+v"(acc1) : "v"(a1), "v"(b));
  }
  asm volatile("s_nop 7\n\ts_nop 7\n\ts_nop 7");
  int rl = (l>>4)*4;
  #pragma unroll
  for (int r=0;r<4;r++){
    gl[w][rl + r][col]      = acc0[r];
    gl[w][rl + r + 16][col] = acc1[r];
  }
  __syncthreads();
  if (tid < 128){
    float gs[4];
    #pragma unroll
    for (int g=0; g<4; g++){
      int cc = g*4 + ju;
      gs[g] = gl[0][n_e][cc] + gl[1][n_e][cc] + gl[2][n_e][cc] + gl[3][n_e][cc];
    }
    float gi = gs[0] + pre_i;
    float gf = gs[1] + pre_f;
    float gg = gs[2] + pre_g;
    float go = gs[3] + pre_o;
    float ii = sigm(gi), ff = sigm(gf), g2 = tanhf(gg), oo = sigm(go);
    float cn = ff*cv + ii*g2;
    c[n_e*512 + j_e] = cn;
    out[n_e*1024 + j_e] = f2b(oo*tanhf(cn));
  }
}

extern "C" void kernel_launch(void* const* d_in, const int* in_sizes, int n_in,
                              void* d_out, int out_size, void* d_ws, size_t ws_size,
                              hipStream_t stream)
{
  const float* inp    = (const float*)d_in[0];
  const float* noise  = (const float*)d_in[1];
  const float* e0f_Wih=(const float*)d_in[2];
  const float* e0f_Whh=(const float*)d_in[3];
  const float* e0f_b  =(const float*)d_in[4];
  const float* e0b_Wih=(const float*)d_in[5];
  const float* e0b_Whh=(const float*)d_in[6];
  const float* e0b_b  =(const float*)d_in[7];
  const float* e1f_Wih=(const float*)d_in[8];
  const float* e1f_Whh=(const float*)d_in[9];
  const float* e1f_b  =(const float*)d_in[10];
  const float* e1b_Wih=(const float*)d_in[11];
  const float* e1b_Whh=(const float*)d_in[12];
  const float* e1b_b  =(const float*)d_in[13];
  const float* df_Wih =(const float*)d_in[14];
  const float* df_Whh =(const float*)d_in[15];
  const float* df_b   =(const float*)d_in[16];
  const float* db_Wih =(const float*)d_in[17];
  const float* db_Whh =(const float*)d_in[18];
  const float* db_b   =(const float*)d_in[19];
  const float* mu_W   =(const float*)d_in[20];
  const float* mu_b   =(const float*)d_in[21];
  const float* sig_W  =(const float*)d_in[22];
  const float* sig_b  =(const float*)d_in[23];
  const float* h0     =(const float*)d_in[24];
  const float* c0     =(const float*)d_in[25];
  const float* ctx_W  =(const float*)d_in[26];
  const float* ctx_b  =(const float*)d_in[27];
  const float* feat_W =(const float*)d_in[28];
  const float* feat_b =(const float*)d_in[29];
  const float* score_W=(const float*)d_in[30];
  const float* score_b=(const float*)d_in[31];

  float* dout = (float*)d_out;
  const long Y_OFF  = 0;
  const long MU_OFF = 8217600;
  const long LV_OFF = 13132800;
  const long MK_OFF = 18048000;

  // ---------------- workspace layout (~178 MB with aliasing) ----------------
  char* ws = (char*)d_ws;
  size_t off = 0;
  auto alloc = [&](size_t bytes)->char*{
    char* p = ws + off; off += (bytes + 255) & ~(size_t)255; return p;
  };
  char* regionA = alloc(25600L*1024*2);   // x1 (enc) -> dec (decoder/head)
  char* regionB = alloc(25600L*1024*2);   // inpb (18MB) -> x2 -> feat chunks
  ushort_t* preFc = (ushort_t*)alloc(3200L*2048*2);  // pre-gate chunk, fwd
  ushort_t* preBc = (ushort_t*)alloc(3200L*2048*2);  // pre-gate chunk, bwd
  ushort_t* zb    = (ushort_t*)alloc(25600L*192*2);
  ushort_t* w_e0f = (ushort_t*)alloc(2048L*352*2);
  ushort_t* w_e0b = (ushort_t*)alloc(2048L*352*2);
  ushort_t* w_e1f = (ushort_t*)alloc(2048L*1024*2);
  ushort_t* w_e1b = (ushort_t*)alloc(2048L*1024*2);
  ushort_t* w_h0f = (ushort_t*)alloc(2048L*512*2);
  ushort_t* w_h0b = (ushort_t*)alloc(2048L*512*2);
  ushort_t* w_h1f = (ushort_t*)alloc(2048L*512*2);
  ushort_t* w_h1b = (ushort_t*)alloc(2048L*512*2);
  ushort_t* w_mu  = (ushort_t*)alloc(256L*1024*2);
  ushort_t* w_sig = (ushort_t*)alloc(256L*1024*2);
  ushort_t* w_dzf = (ushort_t*)alloc(2048L*192*2);
  ushort_t* w_dzb = (ushort_t*)alloc(2048L*192*2);
  ushort_t* BfT   = (ushort_t*)alloc(2048L*1024*2);
  ushort_t* BbT   = (ushort_t*)alloc(2048L*1024*2);
  ushort_t* w_feat= (ushort_t*)alloc(2048L*1024*2);
  ushort_t* w_scr = (ushort_t*)alloc(384L*2048*2);
  float* bdF  = (float*)alloc(2048*4);
  float* bdB  = (float*)alloc(2048*4);
  float* cEF  = (float*)alloc(32L*512*4);
  float* cEB  = (float*)alloc(32L*512*4);
  float* cDF  = (float*)alloc(32L*512*4);
  float* cDB  = (float*)alloc(32L*512*4);
  ushort_t* zerob = (ushort_t*)alloc(32L*1024*2);
  ushort_t* pinit = (ushort_t*)alloc(32L*1024*2);

  ushort_t* x1    = (ushort_t*)regionA;   // [25600][1024]
  ushort_t* dec   = (ushort_t*)regionA;   // alias: written only after x1's last read
  ushort_t* inpb  = (ushort_t*)regionB;   // [25600][352], dead after layer-0 pre chunks
  ushort_t* x2    = (ushort_t*)regionB;   // [25600][1024], written in layer-1 (after inpb dead)
  ushort_t* featc = (ushort_t*)regionB;   // [6400][2048] head chunk (after x2 dead)

  if (ws_size < off){   // not enough scratch: bail with clean zeros
    hipMemsetAsync(d_out, 0, (size_t)out_size*4, stream);
    return;
  }

  auto CVT=[&](const float* s, ushort_t* d, int Rs, int Cs, int c0_, int Cc, int Cd, int Rd){
    long tot = (long)Rd*Cd;
    int blocks = (int)((tot + 255)/256);
    cvt_pad<<<blocks, 256, 0, stream>>>(s, d, Rs, Cs, c0_, Cc, Cd, tot);
  };
  auto GEMM=[&](const ushort_t* A, int lda, const ushort_t* B, int ldb, const float* bias,
                int K, int Nreal, int mode, int ldc, float* oF, ushort_t* oB, int nt, int mt){
    gemm_bt<<<dim3(nt,mt), 256, 0, stream>>>(A, lda, B, ldb, bias, K, Nreal, mode, ldc, oF, oB);
  };
  auto PRE2=[&](const ushort_t* A1, const ushort_t* A2, int lda,
                const ushort_t* B1, const ushort_t* B2, int ldb,
                const float* b1, const float* b2, int K){
    gemm_pre2<<<dim3(16,50), 256, 0, stream>>>(A1, A2, lda, B1, B2, ldb, b1, b2, K, preFc, preBc, 25);
  };

  // ---------------- weight/input conversions ----------------
  CVT(inp,     inpb,  25600, 321, 0, 321, 352, 25600);
  CVT(e0f_Wih, w_e0f, 2048, 321, 0, 321, 352, 2048);
  CVT(e0b_Wih, w_e0b, 2048, 321, 0, 321, 352, 2048);
  CVT(e1f_Wih, w_e1f, 2048, 1024, 0, 1024, 1024, 2048);
  CVT(e1b_Wih, w_e1b, 2048, 1024, 0, 1024, 1024, 2048);
  CVT(e0f_Whh, w_h0f, 2048, 512, 0, 512, 512, 2048);
  CVT(e0b_Whh, w_h0b, 2048, 512, 0, 512, 512, 2048);
  CVT(e1f_Whh, w_h1f, 2048, 512, 0, 512, 512, 2048);
  CVT(e1b_Whh, w_h1b, 2048, 512, 0, 512, 512, 2048);
  CVT(mu_W,    w_mu,  192, 1024, 0, 1024, 1024, 256);
  CVT(sig_W,   w_sig, 192, 1024, 0, 1024, 1024, 256);
  CVT(df_Wih,  w_dzf, 2048, 256, 0, 192, 192, 2048);
  CVT(db_Wih,  w_dzb, 2048, 256, 0, 192, 192, 2048);
  CVT(feat_W,  w_feat,2048, 1024, 0, 1024, 1024, 2048);
  CVT(score_W, w_scr, 321, 2048, 0, 2048, 2048, 384);
  fold_w<<<dim3(4,2048), 256, 0, stream>>>(df_Wih, df_Whh, ctx_W, BfT, 0);
  fold_w<<<dim3(4,2048), 256, 0, stream>>>(db_Wih, db_Whh, ctx_W, BbT, 512);
  fold_b<<<8, 256, 0, stream>>>(df_b, df_Wih, ctx_b, bdF);
  fold_b<<<8, 256, 0, stream>>>(db_b, db_Wih, ctx_b, bdB);
  hipMemsetAsync(zerob, 0, 32L*1024*2, stream);
  hipMemsetAsync(cEF, 0, 32L*512*4, stream);
  hipMemsetAsync(cEB, 0, 32L*512*4, stream);
  dec_init<<<128, 256, 0, stream>>>(h0, c0, pinit, cDF, cDB);

  const int C = 100;            // steps per chunk

  // ---------------- encoder layer 0 (fused pre pair + steps) ----------------
  for (int c = 0; c < 8; c++){
    int f0 = c*C;                     // fwd timesteps [f0, f0+C)
    int b0 = 800 - (c+1)*C;           // bwd timesteps [b0, b0+C), tb descending in step order
    PRE2(inpb + (long)f0*32*352, inpb + (long)b0*32*352, 352, w_e0f, w_e0b, 352, e0f_b, e0b_b, 352);
    for (int j = 0; j < C; j++){
      int s = f0 + j, tf = s, tb = 799 - s;
      const ushort_t* Aff = s ? x1 + (long)(tf-1)*32768        : zerob;
      const ushort_t* Abb = s ? x1 + (long)(tb+1)*32768 + 512  : zerob;
      lstm_step<512><<<256, 256, 0, stream>>>(
        Aff, Abb, preFc + (long)j*65536, preBc + (long)(C-1-j)*65536,
        w_h0f, w_h0b, cEF, cEB,
        x1 + (long)tf*32768, x1 + (long)tb*32768 + 512);
    }
  }

  // ---------------- encoder layer 1 (fused pre pair + steps) ----------------
  hipMemsetAsync(cEF, 0, 32L*512*4, stream);
  hipMemsetAsync(cEB, 0, 32L*512*4, stream);
  for (int c = 0; c < 8; c++){
    int f0 = c*C;
    int b0 = 800 - (c+1)*C;
    PRE2(x1 + (long)f0*32768, x1 + (long)b0*32768, 1024, w_e1f, w_e1b, 1024, e1f_b, e1b_b, 1024);
    for (int j = 0; j < C; j++){
      int s = f0 + j, tf = s, tb = 799 - s;
      const ushort_t* Aff = s ? x2 + (long)(tf-1)*32768        : zerob;
      const ushort_t* Abb = s ? x2 + (long)(tb+1)*32768 + 512  : zerob;
      lstm_step<512><<<256, 256, 0, stream>>>(
        Aff, Abb, preFc + (long)j*65536, preBc + (long)(C-1-j)*65536,
        w_h1f, w_h1b, cEF, cEB,
        x2 + (long)tf*32768, x2 + (long)tb*32768 + 512);
    }
  }

  // ---------------- latent heads + z ----------------
  GEMM(x2, 1024, w_mu,  1024, mu_b,  1024, 192, 3, 0, dout + MU_OFF, nullptr, 2, 200);
  GEMM(x2, 1024, w_sig, 1024, sig_b, 1024, 192, 3, 0, dout + LV_OFF, nullptr, 2, 200);
  z_make<<<(int)((4915200 + 255)/256), 256, 0, stream>>>(dout + MU_OFF, dout + LV_OFF, noise, zb);

  // ---------------- decoder (fused pre pair; both dirs same time order) ----------------
  for (int c = 0; c < 8; c++){
    int f0 = c*C;
    PRE2(zb + (long)f0*32*192, zb + (long)f0*32*192, 192, w_dzf, w_dzb, 192, bdF, bdB, 192);
    for (int j = 0; j < C; j++){
      int t = f0 + j;
      const ushort_t* Ap = t ? dec + (long)(t-1)*32768 : pinit;
      lstm_step<1024><<<256, 256, 0, stream>>>(
        Ap, Ap, preFc + (long)j*65536, preBc + (long)j*65536,
        BfT, BbT, cDF, cDB,
        dec + (long)t*32768, dec + (long)t*32768 + 512);
    }
  }

  // ---------------- output head (4 chunks of 6400 rows; featc aliases regionB) ----------------
  for (int c = 0; c < 4; c++){
    long r0 = (long)c*6400;
    GEMM(dec + r0*1024, 1024, w_feat, 1024, feat_b, 1024, 2048, 2, 2048, nullptr, featc, 16, 50);
    GEMM(featc, 2048, w_scr, 2048, score_b, 2048, 321, 0, 321, dout + Y_OFF + r0*321, nullptr, 3, 50);
  }
  fill1<<<100, 256, 0, stream>>>(dout + MK_OFF, 25600);
}

// Round 18
// 13220.293 us; speedup vs baseline: 71.7770x; 1.0047x over previous
//
#include <hip/hip_runtime.h>

typedef unsigned short ushort_t;
typedef __attribute__((ext_vector_type(4))) float f4;
typedef __attribute__((ext_vector_type(4))) int   i4;

__device__ __forceinline__ float b2f(ushort_t u){
  union { unsigned int i; float f; } v; v.i = ((unsigned int)u) << 16; return v.f;
}
__device__ __forceinline__ ushort_t f2b(float f){
  union { float f; unsigned int i; } v; v.f = f;
  unsigned int u = v.i;
  return (ushort_t)((u + 0x7fffu + ((u >> 16) & 1u)) >> 16);
}
__device__ __forceinline__ float sigm(float x){ return 1.f/(1.f + __expf(-x)); }

// ---------------- fp32 -> bf16 convert with optional col-slice and zero padding ----------------
__global__ void cvt_pad(const float* __restrict__ src, ushort_t* __restrict__ dst,
                        int Rsrc, int Csrc, int col0, int Ccopy, int Cdst, long total){
  long i = (long)blockIdx.x*256 + threadIdx.x;
  if (i >= total) return;
  int r = (int)(i / Cdst), c = (int)(i % Cdst);
  float v = 0.f;
  if (r < Rsrc && c < Ccopy) v = src[(long)r*Csrc + col0 + c];
  dst[i] = f2b(v);
}

// ---------------- decoder weight fold ----------------
__global__ void fold_w(const float* __restrict__ Wih, const float* __restrict__ Whh,
                       const float* __restrict__ ctxW, ushort_t* __restrict__ out, int poff){
  int p = blockIdx.x*256 + threadIdx.x;     // 0..1023
  int q = blockIdx.y;                       // 0..2047
  if (p >= 1024) return;
  float s = 0.f;
  #pragma unroll 8
  for (int e=0;e<64;e++) s += Wih[q*256 + 192 + e] * ctxW[e*1024 + p];
  if (p >= poff && p < poff + 512) s += Whh[q*512 + (p - poff)];
  out[(long)q*1024 + p] = f2b(s);
}

__global__ void fold_b(const float* __restrict__ b, const float* __restrict__ Wih,
                       const float* __restrict__ ctxb, float* __restrict__ out){
  int q = blockIdx.x*256 + threadIdx.x;
  if (q >= 2048) return;
  float s = b[q];
  #pragma unroll 8
  for (int e=0;e<64;e++) s += ctxb[e]*Wih[q*256 + 192 + e];
  out[q] = s;
}

// ---------------- z = mu + exp(0.5*lv)*noise ; reshape [K,S,N,E] -> [S*N, K*E] bf16 ----------------
__global__ void z_make(const float* __restrict__ mu, const float* __restrict__ lv,
                       const float* __restrict__ noise, ushort_t* __restrict__ zb){
  long i = (long)blockIdx.x*256 + threadIdx.x;
  if (i >= 3L*800*32*64) return;
  int e = (int)(i & 63); int n = (int)((i>>6) & 31);
  long r = i >> 11; int s = (int)(r % 800); int k = (int)(r / 800);
  float z = mu[i] + __expf(0.5f*lv[i]) * noise[i];
  zb[((long)(s*32 + n))*192 + k*64 + e] = f2b(z);
}

__global__ void dec_init(const float* __restrict__ h0, const float* __restrict__ c0,
                         ushort_t* __restrict__ prev, float* __restrict__ cDF, float* __restrict__ cDB){
  int i = blockIdx.x*256 + threadIdx.x;
  if (i < 32*1024) prev[i] = f2b(h0[i & 1023]);
  if (i < 32*512){ cDF[i] = c0[i & 511]; cDB[i] = c0[512 + (i & 511)]; }
}

__global__ void fill1(float* __restrict__ p, long n){
  long i = (long)blockIdx.x*256 + threadIdx.x;
  if (i < n) p[i] = 1.f;
}

// ---------------- bf16 MFMA GEMM: C[m][n] = sum_k A[m][k]*B[n][k] + bias[n] ----------------
// A: [M][lda] bf16 (M = gridDim.y*128), B: [Ntiles*128][ldb] bf16 (rows zero-padded), K mult of 32.
// mode 0: fp32 C[m*ldc+n]; 1: bf16; 2: tanh->bf16; 3: fp32 mu-scatter (k=n>>6,e=n&63; out[k*1638400+m*64+e])
#define GLD 40
__global__ __launch_bounds__(256) void gemm_bt(
    const ushort_t* __restrict__ A, int lda,
    const ushort_t* __restrict__ B, int ldb,
    const float* __restrict__ bias, int K, int Nreal, int mode, int ldc,
    float* __restrict__ outF, ushort_t* __restrict__ outB)
{
  __shared__ ushort_t Al[128*GLD];
  __shared__ ushort_t Bl[128*GLD];
  int tid = threadIdx.x;
  int m0 = blockIdx.y * 128;
  int n0 = blockIdx.x * 128;
  int l = tid & 63, w = tid >> 6;
  int wm = w & 1, wn = w >> 1;
  int srow = tid >> 2;       // 0..63
  int scg  = tid & 3;        // 0..3 (16B chunks of the 64B-wide K-tile rows)

  f4 acc[4][4];
  #pragma unroll
  for (int i=0;i<4;i++)
    #pragma unroll
    for (int j=0;j<4;j++) acc[i][j] = (f4){0.f,0.f,0.f,0.f};

  i4 pa0, pa1, pb0, pb1;
  {
    long ab = (long)(m0 + srow)*lda + scg*8;
    pa0 = *(const i4*)&A[ab];
    pa1 = *(const i4*)&A[ab + 64L*lda];
    long bb = (long)(n0 + srow)*ldb + scg*8;
    pb0 = *(const i4*)&B[bb];
    pb1 = *(const i4*)&B[bb + 64L*ldb];
  }
  for (int k0 = 0; k0 < K; k0 += 32){
    __syncthreads();
    *(i4*)&Al[srow*GLD + scg*8]      = pa0;
    *(i4*)&Al[(srow+64)*GLD + scg*8] = pa1;
    *(i4*)&Bl[srow*GLD + scg*8]      = pb0;
    *(i4*)&Bl[(srow+64)*GLD + scg*8] = pb1;
    __syncthreads();
    if (k0 + 32 < K){
      long ab = (long)(m0 + srow)*lda + k0 + 32 + scg*8;
      pa0 = *(const i4*)&A[ab];
      pa1 = *(const i4*)&A[ab + 64L*lda];
      long bb = (long)(n0 + srow)*ldb + k0 + 32 + scg*8;
      pb0 = *(const i4*)&B[bb];
      pb1 = *(const i4*)&B[bb + 64L*ldb];
    }
    int kg = (l>>4)*8;
    i4 av[4], bv[4];
    #pragma unroll
    for (int r=0;r<4;r++)
      av[r] = *(const i4*)&Al[(wm*64 + r*16 + (l&15))*GLD + kg];
    #pragma unroll
    for (int r=0;r<4;r++)
      bv[r] = *(const i4*)&Bl[(wn*64 + r*16 + (l&15))*GLD + kg];
    #pragma unroll
    for (int i=0;i<4;i++)
      #pragma unroll
      for (int j=0;j<4;j++)
        asm volatile("v_mfma_f32_16x16x32_bf16 %0, %1, %2, %0"
                     : "+v"(acc[i][j]) : "v"(av[i]), "v"(bv[j]));
  }
  asm volatile("s_nop 7\n\ts_nop 7\n\ts_nop 7");
  int row_l = (l>>4)*4, col_l = l&15;
  #pragma unroll
  for (int i=0;i<4;i++){
    #pragma unroll
    for (int j=0;j<4;j++){
      int n = n0 + wn*64 + j*16 + col_l;
      if (n >= Nreal) continue;
      float bb = bias[n];
      #pragma unroll
      for (int r=0;r<4;r++){
        int m = m0 + wm*64 + i*16 + row_l + r;
        float v = acc[i][j][r] + bb;
        if (mode == 0){
          outF[(long)m*ldc + n] = v;
        } else if (mode == 1){
          outB[(long)m*ldc + n] = f2b(v);
        } else if (mode == 2){
          outB[(long)m*ldc + n] = f2b(tanhf(v));
        } else {
          outF[(long)(n>>6)*1638400 + (long)m*64 + (n&63)] = v;
        }
      }
    }
  }
}

// ---------------- fused fwd+bwd pre-gate GEMM pair (mode-1, Nreal=2048, ldc=2048) ----------------
// grid dim3(16, 2*mt1): blockIdx.y < mt1 -> problem 1 (fwd), else problem 2 (bwd).
__global__ __launch_bounds__(256) void gemm_pre2(
    const ushort_t* __restrict__ A1, const ushort_t* __restrict__ A2, int lda,
    const ushort_t* __restrict__ B1, const ushort_t* __restrict__ B2, int ldb,
    const float* __restrict__ bias1, const float* __restrict__ bias2, int K,
    ushort_t* __restrict__ out1, ushort_t* __restrict__ out2, int mt1)
{
  __shared__ ushort_t Al[128*GLD];
  __shared__ ushort_t Bl[128*GLD];
  int by = blockIdx.y;
  int sel = by >= mt1;
  const ushort_t* A   = sel ? A2 : A1;
  const ushort_t* B   = sel ? B2 : B1;
  const float* bias   = sel ? bias2 : bias1;
  ushort_t* outB      = sel ? out2 : out1;
  int m0 = (by - (sel ? mt1 : 0)) * 128;
  int n0 = blockIdx.x * 128;
  int tid = threadIdx.x;
  int l = tid & 63, w = tid >> 6;
  int wm = w & 1, wn = w >> 1;
  int srow = tid >> 2;
  int scg  = tid & 3;

  f4 acc[4][4];
  #pragma unroll
  for (int i=0;i<4;i++)
    #pragma unroll
    for (int j=0;j<4;j++) acc[i][j] = (f4){0.f,0.f,0.f,0.f};

  i4 pa0, pa1, pb0, pb1;
  {
    long ab = (long)(m0 + srow)*lda + scg*8;
    pa0 = *(const i4*)&A[ab];
    pa1 = *(const i4*)&A[ab + 64L*lda];
    long bb = (long)(n0 + srow)*ldb + scg*8;
    pb0 = *(const i4*)&B[bb];
    pb1 = *(const i4*)&B[bb + 64L*ldb];
  }
  for (int k0 = 0; k0 < K; k0 += 32){
    __syncthreads();
    *(i4*)&Al[srow*GLD + scg*8]      = pa0;
    *(i4*)&Al[(srow+64)*GLD + scg*8] = pa1;
    *(i4*)&Bl[srow*GLD + scg*8]      = pb0;
    *(i4*)&Bl[(srow+64)*GLD + scg*8] = pb1;
    __syncthreads();
    if (k0 + 32 < K){
      long ab = (long)(m0 + srow)*lda + k0 + 32 + scg*8;
      pa0 = *(const i4*)&A[ab];
      pa1 = *(const i4*)&A[ab + 64L*lda];
      long bb = (long)(n0 + srow)*ldb + k0 + 32 + scg*8;
      pb0 = *(const i4*)&B[bb];
      pb1 = *(const i4*)&B[bb + 64L*ldb];
    }
    int kg = (l>>4)*8;
    i4 av[4], bv[4];
    #pragma unroll
    for (int r=0;r<4;r++)
      av[r] = *(const i4*)&Al[(wm*64 + r*16 + (l&15))*GLD + kg];
    #pragma unroll
    for (int r=0;r<4;r++)
      bv[r] = *(const i4*)&Bl[(wn*64 + r*16 + (l&15))*GLD + kg];
    #pragma unroll
    for (int i=0;i<4;i++)
      #pragma unroll
      for (int j=0;j<4;j++)
        asm volatile("v_mfma_f32_16x16x32_bf16 %0, %1, %2, %0"
                     : "+v"(acc[i][j]) : "v"(av[i]), "v"(bv[j]));
  }
  asm volatile("s_nop 7\n\ts_nop 7\n\ts_nop 7");
  int row_l = (l>>4)*4, col_l = l&15;
  #pragma unroll
  for (int i=0;i<4;i++){
    #pragma unroll
    for (int j=0;j<4;j++){
      int n = n0 + wn*64 + j*16 + col_l;
      float bb = bias[n];
      #pragma unroll
      for (int r=0;r<4;r++){
        int m = m0 + wm*64 + i*16 + row_l + r;
        outB[(long)m*2048 + n] = f2b(acc[i][j][r] + bb);
      }
    }
  }
}

// ---------------- fused LSTM step, all-CU version (round-15 verified) ----------------
// 256 blocks: dir = bx>>7, 4 hidden units u0 = (bx&127)*4 (all 4 gates).
// Waves split K into 4 slices; partial C[32x16] summed via LDS.
// pre/c loads hoisted to kernel entry (latency overlaps MFMA phase).
template<int KA>
__global__ __launch_bounds__(256) void lstm_step(
    const ushort_t* __restrict__ Af, const ushort_t* __restrict__ Ab,  // prev h, row stride 1024
    const ushort_t* __restrict__ preF, const ushort_t* __restrict__ preB, // [32][2048] chunk rows
    const ushort_t* __restrict__ Wf, const ushort_t* __restrict__ Wb,  // [2048][KA], row = g*512+j
    float* __restrict__ cF, float* __restrict__ cB,                    // [32][512]
    ushort_t* __restrict__ outF, ushort_t* __restrict__ outB)          // row stride 1024
{
  __shared__ float gl[4][32][17];
  int tid = threadIdx.x;
  int dir = blockIdx.x >> 7;
  int u0  = (blockIdx.x & 127) << 2;   // 4 hidden units
  const ushort_t* A   = dir ? Ab   : Af;
  const ushort_t* pre = dir ? preB : preF;
  const ushort_t* W   = dir ? Wb   : Wf;
  float* c            = dir ? cB   : cF;
  ushort_t* out       = dir ? outB : outF;

  // ---- hoisted epilogue loads (barrier-independent; owned per-thread) ----
  int n_e = tid >> 2, ju = tid & 3;
  int j_e = u0 + ju;
  float pre_i = 0.f, pre_f = 0.f, pre_g = 0.f, pre_o = 0.f, cv = 0.f;
  if (tid < 128){
    pre_i = b2f(pre[n_e*2048 + j_e]);
    pre_f = b2f(pre[n_e*2048 + 512 + j_e]);
    pre_g = b2f(pre[n_e*2048 + 1024 + j_e]);
    pre_o = b2f(pre[n_e*2048 + 1536 + j_e]);
    cv    = c[n_e*512 + j_e];
  }

  int l = tid & 63, w = tid >> 6;
  int col = l & 15;                    // out col: gate g = col>>2, unit u0+(col&3)
  constexpr int KW = KA/4;             // per-wave K slice
  int kgw = w*KW + (l>>4)*8;
  int wrow = (col>>2)*512 + u0 + (col&3);
  const ushort_t* Wr  = &W[(long)wrow*KA + kgw];
  const ushort_t* Ar0 = &A[col*1024 + kgw];
  const ushort_t* Ar1 = &A[(col+16)*1024 + kgw];
  f4 acc0 = (f4){0.f,0.f,0.f,0.f}, acc1 = (f4){0.f,0.f,0.f,0.f};
  #pragma unroll
  for (int k0=0;k0<KW;k0+=32){
    i4 b  = *(const i4*)&Wr[k0];
    i4 a0 = *(const i4*)&Ar0[k0];
    i4 a1 = *(const i4*)&Ar1[k0];
    asm volatile("v_mfma_f32_16x16x32_bf16 %0, %1, %2, %0" : "+v"(acc0) : "v"(a0), "v"(b));
    asm volatile("v_mfma_f32_16x16x32_bf16 %0, %1, %2, %0" : "+v"(acc1) : "v"(a1), "v"(b));
  }
  asm volatile("s_nop 7\n\ts_nop 7\n\ts_nop 7");
  int rl = (l>>4)*4;
  #pragma unroll
  for (int r=0;r<4;r++){
    gl[w][rl + r][col]      = acc0[r];
    gl[w][rl + r + 16][col] = acc1[r];
  }
  __syncthreads();
  if (tid < 128){
    float gs[4];
    #pragma unroll
    for (int g=0; g<4; g++){
      int cc = g*4 + ju;
      gs[g] = gl[0][n_e][cc] + gl[1][n_e][cc] + gl[2][n_e][cc] + gl[3][n_e][cc];
    }
    float gi = gs[0] + pre_i;
    float gf = gs[1] + pre_f;
    float gg = gs[2] + pre_g;
    float go = gs[3] + pre_o;
    float ii = sigm(gi), ff = sigm(gf), g2 = tanhf(gg), oo = sigm(go);
    float cn = ff*cv + ii*g2;
    c[n_e*512 + j_e] = cn;
    out[n_e*1024 + j_e] = f2b(oo*tanhf(cn));
  }
}

extern "C" void kernel_launch(void* const* d_in, const int* in_sizes, int n_in,
                              void* d_out, int out_size, void* d_ws, size_t ws_size,
                              hipStream_t stream)
{
  const float* inp    = (const float*)d_in[0];
  const float* noise  = (const float*)d_in[1];
  const float* e0f_Wih=(const float*)d_in[2];
  const float* e0f_Whh=(const float*)d_in[3];
  const float* e0f_b  =(const float*)d_in[4];
  const float* e0b_Wih=(const float*)d_in[5];
  const float* e0b_Whh=(const float*)d_in[6];
  const float* e0b_b  =(const float*)d_in[7];
  const float* e1f_Wih=(const float*)d_in[8];
  const float* e1f_Whh=(const float*)d_in[9];
  const float* e1f_b  =(const float*)d_in[10];
  const float* e1b_Wih=(const float*)d_in[11];
  const float* e1b_Whh=(const float*)d_in[12];
  const float* e1b_b  =(const float*)d_in[13];
  const float* df_Wih =(const float*)d_in[14];
  const float* df_Whh =(const float*)d_in[15];
  const float* df_b   =(const float*)d_in[16];
  const float* db_Wih =(const float*)d_in[17];
  const float* db_Whh =(const float*)d_in[18];
  const float* db_b   =(const float*)d_in[19];
  const float* mu_W   =(const float*)d_in[20];
  const float* mu_b   =(const float*)d_in[21];
  const float* sig_W  =(const float*)d_in[22];
  const float* sig_b  =(const float*)d_in[23];
  const float* h0     =(const float*)d_in[24];
  const float* c0     =(const float*)d_in[25];
  const float* ctx_W  =(const float*)d_in[26];
  const float* ctx_b  =(const float*)d_in[27];
  const float* feat_W =(const float*)d_in[28];
  const float* feat_b =(const float*)d_in[29];
  const float* score_W=(const float*)d_in[30];
  const float* score_b=(const float*)d_in[31];

  float* dout = (float*)d_out;
  const long Y_OFF  = 0;
  const long MU_OFF = 8217600;
  const long LV_OFF = 13132800;
  const long MK_OFF = 18048000;

  // ---------------- workspace layout (~204 MB with aliasing) ----------------
  char* ws = (char*)d_ws;
  size_t off = 0;
  auto alloc = [&](size_t bytes)->char*{
    char* p = ws + off; off += (bytes + 255) & ~(size_t)255; return p;
  };
  char* regionA = alloc(25600L*1024*2);   // x1 (enc) -> dec (decoder/head)
  char* regionB = alloc(25600L*1024*2);   // inpb (18MB) -> x2 -> feat chunks
  ushort_t* preFc = (ushort_t*)alloc(6400L*2048*2);  // pre-gate chunk, fwd (C=200)
  ushort_t* preBc = (ushort_t*)alloc(6400L*2048*2);  // pre-gate chunk, bwd
  ushort_t* zb    = (ushort_t*)alloc(25600L*192*2);
  ushort_t* w_e0f = (ushort_t*)alloc(2048L*352*2);
  ushort_t* w_e0b = (ushort_t*)alloc(2048L*352*2);
  ushort_t* w_e1f = (ushort_t*)alloc(2048L*1024*2);
  ushort_t* w_e1b = (ushort_t*)alloc(2048L*1024*2);
  ushort_t* w_h0f = (ushort_t*)alloc(2048L*512*2);
  ushort_t* w_h0b = (ushort_t*)alloc(2048L*512*2);
  ushort_t* w_h1f = (ushort_t*)alloc(2048L*512*2);
  ushort_t* w_h1b = (ushort_t*)alloc(2048L*512*2);
  ushort_t* w_mu  = (ushort_t*)alloc(256L*1024*2);
  ushort_t* w_sig = (ushort_t*)alloc(256L*1024*2);
  ushort_t* w_dzf = (ushort_t*)alloc(2048L*192*2);
  ushort_t* w_dzb = (ushort_t*)alloc(2048L*192*2);
  ushort_t* BfT   = (ushort_t*)alloc(2048L*1024*2);
  ushort_t* BbT   = (ushort_t*)alloc(2048L*1024*2);
  ushort_t* w_feat= (ushort_t*)alloc(2048L*1024*2);
  ushort_t* w_scr = (ushort_t*)alloc(384L*2048*2);
  float* bdF  = (float*)alloc(2048*4);
  float* bdB  = (float*)alloc(2048*4);
  float* cEF  = (float*)alloc(32L*512*4);
  float* cEB  = (float*)alloc(32L*512*4);
  float* cDF  = (float*)alloc(32L*512*4);
  float* cDB  = (float*)alloc(32L*512*4);
  ushort_t* zerob = (ushort_t*)alloc(32L*1024*2);
  ushort_t* pinit = (ushort_t*)alloc(32L*1024*2);

  ushort_t* x1    = (ushort_t*)regionA;   // [25600][1024]
  ushort_t* dec   = (ushort_t*)regionA;   // alias: written only after x1's last read
  ushort_t* inpb  = (ushort_t*)regionB;   // [25600][352], dead after layer-0 pre chunks
  ushort_t* x2    = (ushort_t*)regionB;   // [25600][1024], written in layer-1 (after inpb dead)
  ushort_t* featc = (ushort_t*)regionB;   // [6400][2048] head chunk (after x2 dead)

  if (ws_size < off){   // not enough scratch: bail with clean zeros
    hipMemsetAsync(d_out, 0, (size_t)out_size*4, stream);
    return;
  }

  auto CVT=[&](const float* s, ushort_t* d, int Rs, int Cs, int c0_, int Cc, int Cd, int Rd){
    long tot = (long)Rd*Cd;
    int blocks = (int)((tot + 255)/256);
    cvt_pad<<<blocks, 256, 0, stream>>>(s, d, Rs, Cs, c0_, Cc, Cd, tot);
  };
  auto GEMM=[&](const ushort_t* A, int lda, const ushort_t* B, int ldb, const float* bias,
                int K, int Nreal, int mode, int ldc, float* oF, ushort_t* oB, int nt, int mt){
    gemm_bt<<<dim3(nt,mt), 256, 0, stream>>>(A, lda, B, ldb, bias, K, Nreal, mode, ldc, oF, oB);
  };
  auto PRE2=[&](const ushort_t* A1, const ushort_t* A2, int lda,
                const ushort_t* B1, const ushort_t* B2, int ldb,
                const float* b1, const float* b2, int K){
    gemm_pre2<<<dim3(16,100), 256, 0, stream>>>(A1, A2, lda, B1, B2, ldb, b1, b2, K, preFc, preBc, 50);
  };

  // ---------------- weight/input conversions ----------------
  CVT(inp,     inpb,  25600, 321, 0, 321, 352, 25600);
  CVT(e0f_Wih, w_e0f, 2048, 321, 0, 321, 352, 2048);
  CVT(e0b_Wih, w_e0b, 2048, 321, 0, 321, 352, 2048);
  CVT(e1f_Wih, w_e1f, 2048, 1024, 0, 1024, 1024, 2048);
  CVT(e1b_Wih, w_e1b, 2048, 1024, 0, 1024, 1024, 2048);
  CVT(e0f_Whh, w_h0f, 2048, 512, 0, 512, 512, 2048);
  CVT(e0b_Whh, w_h0b, 2048, 512, 0, 512, 512, 2048);
  CVT(e1f_Whh, w_h1f, 2048, 512, 0, 512, 512, 2048);
  CVT(e1b_Whh, w_h1b, 2048, 512, 0, 512, 512, 2048);
  CVT(mu_W,    w_mu,  192, 1024, 0, 1024, 1024, 256);
  CVT(sig_W,   w_sig, 192, 1024, 0, 1024, 1024, 256);
  CVT(df_Wih,  w_dzf, 2048, 256, 0, 192, 192, 2048);
  CVT(db_Wih,  w_dzb, 2048, 256, 0, 192, 192, 2048);
  CVT(feat_W,  w_feat,2048, 1024, 0, 1024, 1024, 2048);
  CVT(score_W, w_scr, 321, 2048, 0, 2048, 2048, 384);
  fold_w<<<dim3(4,2048), 256, 0, stream>>>(df_Wih, df_Whh, ctx_W, BfT, 0);
  fold_w<<<dim3(4,2048), 256, 0, stream>>>(db_Wih, db_Whh, ctx_W, BbT, 512);
  fold_b<<<8, 256, 0, stream>>>(df_b, df_Wih, ctx_b, bdF);
  fold_b<<<8, 256, 0, stream>>>(db_b, db_Wih, ctx_b, bdB);
  hipMemsetAsync(zerob, 0, 32L*1024*2, stream);
  hipMemsetAsync(cEF, 0, 32L*512*4, stream);
  hipMemsetAsync(cEB, 0, 32L*512*4, stream);
  dec_init<<<128, 256, 0, stream>>>(h0, c0, pinit, cDF, cDB);

  const int C = 200;            // steps per chunk

  // ---------------- encoder layer 0 (fused pre pair + steps) ----------------
  for (int c = 0; c < 4; c++){
    int f0 = c*C;                     // fwd timesteps [f0, f0+C)
    int b0 = 800 - (c+1)*C;           // bwd timesteps [b0, b0+C), tb descending in step order
    PRE2(inpb + (long)f0*32*352, inpb + (long)b0*32*352, 352, w_e0f, w_e0b, 352, e0f_b, e0b_b, 352);
    for (int j = 0; j < C; j++){
      int s = f0 + j, tf = s, tb = 799 - s;
      const ushort_t* Aff = s ? x1 + (long)(tf-1)*32768        : zerob;
      const ushort_t* Abb = s ? x1 + (long)(tb+1)*32768 + 512  : zerob;
      lstm_step<512><<<256, 256, 0, stream>>>(
        Aff, Abb, preFc + (long)j*65536, preBc + (long)(C-1-j)*65536,
        w_h0f, w_h0b, cEF, cEB,
        x1 + (long)tf*32768, x1 + (long)tb*32768 + 512);
    }
  }

  // ---------------- encoder layer 1 (fused pre pair + steps) ----------------
  hipMemsetAsync(cEF, 0, 32L*512*4, stream);
  hipMemsetAsync(cEB, 0, 32L*512*4, stream);
  for (int c = 0; c < 4; c++){
    int f0 = c*C;
    int b0 = 800 - (c+1)*C;
    PRE2(x1 + (long)f0*32768, x1 + (long)b0*32768, 1024, w_e1f, w_e1b, 1024, e1f_b, e1b_b, 1024);
    for (int j = 0; j < C; j++){
      int s = f0 + j, tf = s, tb = 799 - s;
      const ushort_t* Aff = s ? x2 + (long)(tf-1)*32768        : zerob;
      const ushort_t* Abb = s ? x2 + (long)(tb+1)*32768 + 512  : zerob;
      lstm_step<512><<<256, 256, 0, stream>>>(
        Aff, Abb, preFc + (long)j*65536, preBc + (long)(C-1-j)*65536,
        w_h1f, w_h1b, cEF, cEB,
        x2 + (long)tf*32768, x2 + (long)tb*32768 + 512);
    }
  }

  // ---------------- latent heads + z ----------------
  GEMM(x2, 1024, w_mu,  1024, mu_b,  1024, 192, 3, 0, dout + MU_OFF, nullptr, 2, 200);
  GEMM(x2, 1024, w_sig, 1024, sig_b, 1024, 192, 3, 0, dout + LV_OFF, nullptr, 2, 200);
  z_make<<<(int)((4915200 + 255)/256), 256, 0, stream>>>(dout + MU_OFF, dout + LV_OFF, noise, zb);

  // ---------------- decoder (fused pre pair; both dirs same time order) ----------------
  for (int c = 0; c < 4; c++){
    int f0 = c*C;
    PRE2(zb + (long)f0*32*192, zb + (long)f0*32*192, 192, w_dzf, w_dzb, 192, bdF, bdB, 192);
    for (int j = 0; j < C; j++){
      int t = f0 + j;
      const ushort_t* Ap = t ? dec + (long)(t-1)*32768 : pinit;
      lstm_step<1024><<<256, 256, 0, stream>>>(
        Ap, Ap, preFc + (long)j*65536, preBc + (long)j*65536,
        BfT, BbT, cDF, cDB,
        dec + (long)t*32768, dec + (long)t*32768 + 512);
    }
  }

  // ---------------- output head (4 chunks of 6400 rows; featc aliases regionB) ----------------
  for (int c = 0; c < 4; c++){
    long r0 = (long)c*6400;
    GEMM(dec + r0*1024, 1024, w_feat, 1024, feat_b, 1024, 2048, 2, 2048, nullptr, featc, 16, 50);
    GEMM(featc, 2048, w_scr, 2048, score_b, 2048, 321, 0, 321, dout + Y_OFF + r0*321, nullptr, 3, 50);
  }
  fill1<<<100, 256, 0, stream>>>(dout + MK_OFF, 25600);
}